// Round 3
// baseline (554.361 us; speedup 1.0000x reference)
//
#include <hip/hip_runtime.h>

typedef unsigned short u16;
typedef __attribute__((ext_vector_type(8))) short bf16x8;
typedef __attribute__((ext_vector_type(8))) unsigned short u16x8;
typedef __attribute__((ext_vector_type(4))) float f32x4;

#define N_NODES 10000
#define E_EDGES 160000
#define CX_N 2560000
#define W_N  65536
#define WB_N 4194304
// big canon total = CX_N + 4*W_N + WB_N = 7016448 elems = 877056 x8 = 3426 blocks
#define CANON_BIG_BLOCKS 3426
#define HIST_BLOCKS 79          // 79*2048 = 161792 >= E_EDGES

__device__ __forceinline__ float b2f(u16 u) {
  union { unsigned i; float f; } c; c.i = ((unsigned)u) << 16; return c.f;
}
__device__ __forceinline__ u16 f2b(float f) {
  union { float f; unsigned i; } c; c.f = f;
  unsigned i = c.i;
  return (u16)((i + 0x7FFFu + ((i >> 16) & 1u)) >> 16);  // RNE
}

// ---------------------------------------------------------------------------
// Dtype detection (bf16 vs f32 inputs), R2-verified.
// ---------------------------------------------------------------------------
__global__ void detect_kernel(const unsigned* __restrict__ w, int* __restrict__ flag) {
  int t = threadIdx.x;  // 64 threads
  int cnt = 0;
  for (int i = t; i < 1024; i += 64) {
    unsigned e = (w[i] >> 7) & 0xFF;
    cnt += (e >= 100 && e <= 145) ? 1 : 0;
  }
  for (int o = 32; o; o >>= 1) cnt += __shfl_xor(cnt, o);
  if (t == 0) *flag = (cnt >= 512) ? 1 : 0;
}

// ---------------------------------------------------------------------------
// canon_all (R13-verified, ~7 µs tail win): ONE launch = 4 canons + hist.
// ---------------------------------------------------------------------------
__global__ void canon_all_kernel(const void* sx, const void* swc, const void* sw1,
                                 const void* sw2, const void* sw4, const void* swB,
                                 const void* sbc, const void* sb1, const void* sb2,
                                 const void* sb4, const void* sw3, const void* sbB,
                                 const void* sb3,
                                 u16* __restrict__ dstBase,   // = cx (contiguous run)
                                 u16* cbc, u16* cb1, u16* cb2, u16* cb4,
                                 u16* cw3, u16* cbB, u16* cb3,
                                 const int* __restrict__ ei, int* __restrict__ count,
                                 const int* __restrict__ flag) {
  int b = blockIdx.x;
  int f = *flag;
  if (b < CANON_BIG_BLOCKS) {
    long e = ((long)b * 256 + threadIdx.x) * 8;   // elem offset (8-aligned)
    const void* src; long so;
    if (e < CX_N)                { src = sx;  so = e; }
    else if (e < CX_N + W_N)     { src = swc; so = e - CX_N; }
    else if (e < CX_N + 2 * W_N) { src = sw1; so = e - (CX_N + W_N); }
    else if (e < CX_N + 3 * W_N) { src = sw2; so = e - (CX_N + 2 * W_N); }
    else if (e < CX_N + 4 * W_N) { src = sw4; so = e - (CX_N + 3 * W_N); }
    else                         { src = swB; so = e - (CX_N + 4 * W_N); }
    if (f) {
      u16x8 v = *((const u16x8*)((const u16*)src + so));
      *(u16x8*)(dstBase + e) = v;
    } else {
      const float* fp = (const float*)src + so;
      float4 a = *(const float4*)fp;
      float4 c = *(const float4*)(fp + 4);
      u16x8 o;
      o[0] = f2b(a.x); o[1] = f2b(a.y); o[2] = f2b(a.z); o[3] = f2b(a.w);
      o[4] = f2b(c.x); o[5] = f2b(c.y); o[6] = f2b(c.z); o[7] = f2b(c.w);
      *(u16x8*)(dstBase + e) = o;
    }
  } else if (b == CANON_BIG_BLOCKS) {
    int t = threadIdx.x;
    const void* srcs[7] = {sbc, sb1, sb2, sb4, sw3, sbB, sb3};
    u16* dsts[7] = {cbc, cb1, cb2, cb4, cw3, cbB, cb3};
    const int ns[7] = {256, 256, 256, 256, 256, 64, 1};
#pragma unroll
    for (int k = 0; k < 7; ++k) {
      if (t < ns[k]) {
        if (f) dsts[k][t] = ((const u16*)srcs[k])[t];
        else   dsts[k][t] = f2b(((const float*)srcs[k])[t]);
      }
    }
  } else {
    int base = (b - CANON_BIG_BLOCKS - 1) * 2048 + threadIdx.x * 8;
#pragma unroll
    for (int k = 0; k < 8; ++k) {
      int i = base + k;
      if (i < E_EDGES) atomicAdd(&count[ei[E_EDGES + i]], 1);
    }
  }
}

// ---------------------------------------------------------------------------
// GEMM core (m97-style, R5/R12-verified): 128x128 tile, BK=64, 4 waves,
// global_load_lds 16B + XOR chunk swizzle (0 bank conflicts).
// (R14/R15 schedule rewrites regressed — reverted to round-0 form.)
// ---------------------------------------------------------------------------
__device__ __forceinline__ void stage_async(const u16* __restrict__ src, int stride,
                                            int row0, int maxRow, int k0,
                                            u16* lds, int w, int lane) {
  int rsel = lane >> 3;
  int gch = (lane & 7) ^ rsel;
#pragma unroll
  for (int i = 0; i < 4; ++i) {
    int rb = (w * 4 + i) * 8;
    int grow = row0 + rb + rsel;
    grow = grow > maxRow ? maxRow : grow;
    const u16* gp = src + (size_t)grow * stride + k0 + gch * 8;
    u16* lp = lds + rb * 64;
    __builtin_amdgcn_global_load_lds(
        (const __attribute__((address_space(1))) void*)gp,
        (__attribute__((address_space(3))) void*)lp, 16, 0, 0);
  }
}

__device__ __forceinline__ void mma_tile(const u16* lA, const u16* lB,
                                         f32x4 acc[4][4], int wr, int wc, int lane) {
#pragma unroll
  for (int ks = 0; ks < 2; ++ks) {
    bf16x8 af[4], bfr[4];
    int g = ks * 4 + (lane >> 4);
#pragma unroll
    for (int t = 0; t < 4; ++t) {
      int rowA = wr * 64 + t * 16 + (lane & 15);
      af[t] = *(const bf16x8*)(lA + rowA * 64 + ((g ^ (rowA & 7)) * 8));
      int rowB = wc * 64 + t * 16 + (lane & 15);
      bfr[t] = *(const bf16x8*)(lB + rowB * 64 + ((g ^ (rowB & 7)) * 8));
    }
#pragma unroll
    for (int ti = 0; ti < 4; ++ti)
#pragma unroll
      for (int tj = 0; tj < 4; ++tj)
        acc[ti][tj] = __builtin_amdgcn_mfma_f32_16x16x32_bf16(af[ti], bfr[tj],
                                                              acc[ti][tj], 0, 0, 0);
  }
}

template <bool RELU, bool F32OUT>
__global__ __launch_bounds__(256, 2)
void gemm_kernel(const u16* __restrict__ A, const u16* __restrict__ B,
                 const u16* __restrict__ bias, float* __restrict__ outF,
                 u16* __restrict__ outB, int NN, int J, int K) {
  __shared__ u16 lA[128 * 64];
  __shared__ u16 lB[128 * 64];
  int lane = threadIdx.x & 63;
  int w = threadIdx.x >> 6;
  int wr = w >> 1, wc = w & 1;
  int n0 = blockIdx.y * 128;
  int j0 = blockIdx.x * 128;
  f32x4 acc[4][4];
#pragma unroll
  for (int i = 0; i < 4; ++i)
#pragma unroll
    for (int j = 0; j < 4; ++j) acc[i][j] = (f32x4){0.f, 0.f, 0.f, 0.f};

  for (int kt = 0; kt < K; kt += 64) {
    stage_async(A, K, n0, NN - 1, kt, lA, w, lane);
    stage_async(B, K, j0, J - 1, kt, lB, w, lane);
    __syncthreads();
    mma_tile(lA, lB, acc, wr, wc, lane);
    __syncthreads();
  }

#pragma unroll
  for (int ti = 0; ti < 4; ++ti)
#pragma unroll
    for (int tj = 0; tj < 4; ++tj) {
      int col = j0 + wc * 64 + tj * 16 + (lane & 15);
      float bv = bias ? b2f(bias[col]) : 0.0f;
#pragma unroll
      for (int r = 0; r < 4; ++r) {
        int row = n0 + wr * 64 + ti * 16 + ((lane >> 4) << 2) + r;
        if (row < NN) {
          float v = acc[ti][tj][r] + bv;
          if (RELU) v = fmaxf(v, 0.0f);
          if (F32OUT) outF[(size_t)row * J + col] = v;
          else        outB[(size_t)row * J + col] = f2b(v);
        }
      }
    }
}

// ---------------------------------------------------------------------------
// Fused lin2+lin3+lin4 (R10-verified, round-0 form).
// ---------------------------------------------------------------------------
__global__ __launch_bounds__(256, 2)
void gemm_fused234_kernel(const u16* __restrict__ A, const u16* __restrict__ B,
                          const u16* __restrict__ bias, const u16* __restrict__ w3,
                          float* __restrict__ out1acc, u16* __restrict__ x2v, int NN) {
  __shared__ u16 lA[128 * 64];
  __shared__ u16 lB[128 * 64];
  int lane = threadIdx.x & 63;
  int w = threadIdx.x >> 6;
  int wr = w >> 1, wc = w & 1;
  int n0 = blockIdx.y * 128;
  int j0 = blockIdx.x * 128;
  f32x4 acc[4][4];
#pragma unroll
  for (int i = 0; i < 4; ++i)
#pragma unroll
    for (int j = 0; j < 4; ++j) acc[i][j] = (f32x4){0.f, 0.f, 0.f, 0.f};

  for (int kt = 0; kt < 256; kt += 64) {
    stage_async(A, 256, n0, NN - 1, kt, lA, w, lane);
    stage_async(B, 256, j0, 511, kt, lB, w, lane);
    __syncthreads();
    mma_tile(lA, lB, acc, wr, wc, lane);
    __syncthreads();
  }

  if (j0 < 256) {
    float part[4][4];
#pragma unroll
    for (int ti = 0; ti < 4; ++ti)
#pragma unroll
      for (int r = 0; r < 4; ++r) part[ti][r] = 0.0f;
#pragma unroll
    for (int ti = 0; ti < 4; ++ti)
#pragma unroll
      for (int tj = 0; tj < 4; ++tj) {
        int col = j0 + wc * 64 + tj * 16 + (lane & 15);
        float bv = b2f(bias[col]);
        float wv = b2f(w3[col]);
#pragma unroll
        for (int r = 0; r < 4; ++r) {
          float v = fmaxf(acc[ti][tj][r] + bv, 0.0f);
          part[ti][r] += v * wv;
        }
      }
#pragma unroll
    for (int ti = 0; ti < 4; ++ti)
#pragma unroll
      for (int r = 0; r < 4; ++r) {
        float s = part[ti][r];
        s += __shfl_xor(s, 1);
        s += __shfl_xor(s, 2);
        s += __shfl_xor(s, 4);
        s += __shfl_xor(s, 8);
        if ((lane & 15) == 0) {
          int row = n0 + wr * 64 + ti * 16 + ((lane >> 4) << 2) + r;
          if (row < NN) unsafeAtomicAdd(&out1acc[row], s);
        }
      }
  } else {
#pragma unroll
    for (int ti = 0; ti < 4; ++ti)
#pragma unroll
      for (int tj = 0; tj < 4; ++tj) {
        int col = j0 + wc * 64 + tj * 16 + (lane & 15);
        float bv = b2f(bias[col]);
#pragma unroll
        for (int r = 0; r < 4; ++r) {
          int row = n0 + wr * 64 + ti * 16 + ((lane >> 4) << 2) + r;
          if (row < NN) {
            float v = fmaxf(acc[ti][tj][r] + bv, 0.0f);
            x2v[(size_t)row * 256 + (col - 256)] = f2b(v);
          }
        }
      }
  }
}

// ---------------------------------------------------------------------------
// R16 bilinear: REGISTER-STREAMING GEMM — no LDS, no barriers. R13/R15 were
// LDS-read-BW-bound (128-384 KB LDS reads per 8.4 MF block, barrier-lockstep
// bursts). MFMA fragments have native global layout: per lane 16B contiguous
// at row*512 + k0 + (lane>>4)*16 — one global_load_dwordx4, 16 full 64B
// lines/wave, zero waste, straight from L2 (W=8.4MB, x2=5MB: L2/L3-hot).
// Index arithmetic byte-identical to verified R13 path. Grid (n=79, W=128):
// consecutive blocks share the L2-fit x2 panel; W swept once per n-tile.
// ---------------------------------------------------------------------------
__global__ __launch_bounds__(256, 2)
void bilinear_stream_kernel(const u16* __restrict__ x2v, const u16* __restrict__ W,
                            float* __restrict__ out2acc, int NN) {
  int lane = threadIdx.x & 63;
  int w = threadIdx.x >> 6;
  int wr = w >> 1, wc = w & 1;
  int n0 = blockIdx.x * 128;          // n-tile
  int rm0 = blockIdx.y * 128;         // W row-tile
  int region = blockIdx.y >> 1;
  int i0 = (blockIdx.y & 1) * 128;    // x2-column offset of this W block

  // fragment base pointers (row-clamped for the 10000..10111 overrun rows)
  const u16* pA[4];
  const u16* pB[4];
#pragma unroll
  for (int t = 0; t < 4; ++t) {
    int rA = n0 + wr * 64 + t * 16 + (lane & 15);
    rA = rA < NN ? rA : NN - 1;
    pA[t] = x2v + (size_t)rA * 256 + (lane >> 4) * 8;
    int rB = rm0 + wc * 64 + t * 16 + (lane & 15);
    pB[t] = W + (size_t)rB * 256 + (lane >> 4) * 8;
  }

  f32x4 acc[4][4];
#pragma unroll
  for (int i = 0; i < 4; ++i)
#pragma unroll
    for (int j = 0; j < 4; ++j) acc[i][j] = (f32x4){0.f, 0.f, 0.f, 0.f};

#pragma unroll
  for (int ks = 0; ks < 8; ++ks) {      // K = 8 x 32
    bf16x8 af[4], bfr[4];
#pragma unroll
    for (int t = 0; t < 4; ++t) af[t] = *(const bf16x8*)(pA[t] + ks * 32);
#pragma unroll
    for (int t = 0; t < 4; ++t) bfr[t] = *(const bf16x8*)(pB[t] + ks * 32);
#pragma unroll
    for (int ti = 0; ti < 4; ++ti)
#pragma unroll
      for (int tj = 0; tj < 4; ++tj)
        acc[ti][tj] = __builtin_amdgcn_mfma_f32_16x16x32_bf16(af[ti], bfr[tj],
                                                              acc[ti][tj], 0, 0, 0);
  }

  // epilogue: out2[row, region] += sum over this block's 128 i-cols of
  // acc * x2[row, i]; x2 re-read as scalar L2 loads (4x32B per wave).
#pragma unroll
  for (int ti = 0; ti < 4; ++ti)
#pragma unroll
    for (int r = 0; r < 4; ++r) {
      int row = n0 + wr * 64 + ti * 16 + ((lane >> 4) << 2) + r;
      int rc = row < NN ? row : NN - 1;
      const u16* xr = x2v + (size_t)rc * 256 + i0 + wc * 64 + (lane & 15);
      float s = 0.0f;
#pragma unroll
      for (int tj = 0; tj < 4; ++tj)
        s += acc[ti][tj][r] * b2f(xr[tj * 16]);
      s += __shfl_xor(s, 1);
      s += __shfl_xor(s, 2);
      s += __shfl_xor(s, 4);
      s += __shfl_xor(s, 8);
      if ((lane & 15) == 0 && row < NN)
        unsafeAtomicAdd(&out2acc[(size_t)row * 64 + region], s);
    }
}

// --------------------- edge sort (scan/place) + gather ----------------------
__global__ void scan_kernel(const int* __restrict__ count, int* __restrict__ start,
                            int* __restrict__ cursor, float* __restrict__ dinv) {
  __shared__ int wsum[16];
  __shared__ int carry_s;
  int t = threadIdx.x;          // 1024 threads = 16 waves
  int wv = t >> 6, ln = t & 63;
  if (t == 0) carry_s = 0;
  __syncthreads();
  for (int base = 0; base < N_NODES; base += 1024) {
    int i = base + t;
    int v = (i < N_NODES) ? count[i] : 0;
    int s = v;
#pragma unroll
    for (int o = 1; o < 64; o <<= 1) {
      int u = __shfl_up(s, o);
      if (ln >= o) s += u;
    }
    if (ln == 63) wsum[wv] = s;
    __syncthreads();
    if (wv == 0) {
      int x = (ln < 16) ? wsum[ln] : 0;
#pragma unroll
      for (int o = 1; o < 16; o <<= 1) {
        int u = __shfl_up(x, o);
        if (ln >= o) x += u;
      }
      if (ln < 16) wsum[ln] = x;
    }
    __syncthreads();
    int excl = s - v + (wv ? wsum[wv - 1] : 0) + carry_s;
    if (i < N_NODES) {
      start[i] = excl;
      cursor[i] = excl;
      dinv[i] = rsqrtf(1.0f + (float)v);
    }
    __syncthreads();
    if (t == 0) carry_s += wsum[15];
    __syncthreads();
  }
}

__global__ void place_kernel(const int* __restrict__ ei, int* __restrict__ cursor,
                             int* __restrict__ order) {
  int i = blockIdx.x * 256 + threadIdx.x;
  if (i >= E_EDGES) return;
  int d = ei[E_EDGES + i];
  int pos = atomicAdd(&cursor[d], 1);
  order[pos] = i;
}

__global__ void gather_kernel(const int* __restrict__ ei, const int* __restrict__ order,
                              const int* __restrict__ start, const int* __restrict__ count,
                              const float* __restrict__ dinv, const float* __restrict__ xw,
                              const u16* __restrict__ conv_b, const u16* __restrict__ x,
                              u16* __restrict__ x0) {
  int node = (blockIdx.x * blockDim.x + threadIdx.x) >> 6;
  int lane = threadIdx.x & 63;
  if (node >= N_NODES) return;
  int s0 = start[node], cnt = count[node];
  float dn = dinv[node];
  float ax = 0.f, ay = 0.f, az = 0.f, aw = 0.f;
  for (int base = 0; base < cnt; base += 64) {
    int rem = cnt - base;
    int m = rem < 64 ? rem : 64;
    int eid = (lane < m) ? order[s0 + base + lane] : 0;
    int s = (lane < m) ? ei[eid] : 0;
    float nrm = (lane < m) ? dinv[s] * dn : 0.f;
    for (int j = 0; j < m; ++j) {
      int sj = __shfl(s, j);
      float nj = __shfl(nrm, j);
      float4 v = *((const float4*)(xw + (size_t)sj * 256) + lane);
      ax += nj * v.x; ay += nj * v.y; az += nj * v.z; aw += nj * v.w;
    }
  }
  float4 sv = *((const float4*)(xw + (size_t)node * 256) + lane);
  float slw = dn * dn;
  const u16* bb = conv_b + lane * 4;
  const u16* xr = x + (size_t)node * 256 + lane * 4;
  u16 o[4];
  float vals[4] = {ax + slw * sv.x, ay + slw * sv.y, az + slw * sv.z, aw + slw * sv.w};
#pragma unroll
  for (int j = 0; j < 4; ++j) {
    float v = vals[j] + b2f(bb[j]);
    v = fmaxf(v, 0.0f) + b2f(xr[j]);
    o[j] = f2b(v);
  }
  *((ushort4*)(x0 + (size_t)node * 256) + lane) = make_ushort4(o[0], o[1], o[2], o[3]);
}

// ------------------------------- final output -------------------------------
__global__ void out_final_kernel(const float* __restrict__ out1acc,
                                 const float* __restrict__ out2acc,
                                 const u16* __restrict__ b3, const u16* __restrict__ bb,
                                 void* __restrict__ dout, const int* __restrict__ flag) {
  int idx = blockIdx.x * 256 + threadIdx.x;
  int f = *flag;
  if (idx < N_NODES) {
    float v = out1acc[idx] + b2f(b3[0]);
    if (f) ((u16*)dout)[idx] = f2b(v);
    else   ((float*)dout)[idx] = v;
  } else if (idx < N_NODES + N_NODES * 64) {
    int k = idx - N_NODES;
    float v = out2acc[k] + b2f(bb[k & 63]);
    if (f) ((u16*)dout)[idx] = f2b(v);
    else   ((float*)dout)[idx] = v;
  }
}

// ----------------------------------------------------------------------------
extern "C" void kernel_launch(void* const* d_in, const int* in_sizes, int n_in,
                              void* d_out, int out_size, void* d_ws, size_t ws_size,
                              hipStream_t stream) {
  const int* ei = (const int*)d_in[1];

  float* ws      = (float*)d_ws;
  float* xw      = ws;                          // [N,256] f32
  int*   count   = (int*)(xw + N_NODES * 256);  // [N]
  int*   start   = count + 10240;               // [N]
  int*   cursor  = start + 10240;               // [N]
  int*   order   = cursor + 10240;              // [E]
  float* dinv    = (float*)(order + E_EDGES);   // [N]
  float* out1acc = dinv + 10240;                // [N] (padded 10240)
  float* out2acc = out1acc + 10240;             // [N,64] (adjacent: one memset)
  u16* x0  = (u16*)(out2acc + N_NODES * 64);    // [N,256] bf16
  u16* x0m = x0 + N_NODES * 256;
  u16* x2v = x0m + N_NODES * 256;
  // canonical bf16 inputs — cx..cwB CONTIGUOUS (canon_all relies on this)
  u16* cx  = x2v + N_NODES * 256;
  u16* cwc = cx + CX_N;
  u16* cw1 = cwc + W_N;
  u16* cw2 = cw1 + W_N;                         // cw2, cw4 contiguous = [512,256]
  u16* cw4 = cw2 + W_N;
  u16* cwB = cw4 + W_N;
  u16* cbc = cwB + WB_N;
  u16* cb1 = cbc + 256;
  u16* cb2 = cb1 + 256;                         // cb2, cb4 contiguous = [512]
  u16* cb4 = cb2 + 256;
  u16* cw3 = cb4 + 256;
  u16* cbB = cw3 + 256;
  u16* cb3 = cbB + 64;
  int* flag = (int*)(cb3 + 16);

  hipMemsetAsync(count, 0, N_NODES * sizeof(int), stream);
  hipMemsetAsync(out1acc, 0, (10240 + (size_t)N_NODES * 64) * sizeof(float), stream);

  detect_kernel<<<1, 64, 0, stream>>>((const unsigned*)d_in[0], flag);

  canon_all_kernel<<<CANON_BIG_BLOCKS + 1 + HIST_BLOCKS, 256, 0, stream>>>(
      d_in[0], d_in[2], d_in[4], d_in[6], d_in[10], d_in[12],
      d_in[3], d_in[5], d_in[7], d_in[11], d_in[8], d_in[13], d_in[9],
      cx, cbc, cb1, cb2, cb4, cw3, cbB, cb3,
      ei, count, flag);

  scan_kernel<<<1, 1024, 0, stream>>>(count, start, cursor, dinv);
  place_kernel<<<(E_EDGES + 255) / 256, 256, 0, stream>>>(ei, cursor, order);

  gemm_kernel<false, true><<<dim3(2, 79), 256, 0, stream>>>(
      cx, cwc, nullptr, xw, nullptr, N_NODES, 256, 256);

  gather_kernel<<<(N_NODES * 64 + 255) / 256, 256, 0, stream>>>(
      ei, order, start, count, dinv, xw, cbc, cx, x0);

  gemm_kernel<true, false><<<dim3(2, 79), 256, 0, stream>>>(
      x0, cw1, cb1, nullptr, x0m, N_NODES, 256, 256);

  gemm_fused234_kernel<<<dim3(4, 79), 256, 0, stream>>>(
      x0m, cw2, cb2, cw3, out1acc, x2v, N_NODES);

  bilinear_stream_kernel<<<dim3(79, 128), 256, 0, stream>>>(x2v, cwB, out2acc, N_NODES);

  out_final_kernel<<<(N_NODES * 65 + 255) / 256, 256, 0, stream>>>(
      out1acc, out2acc, cb3, cbB, d_out, flag);
}

// Round 5
// 469.797 us; speedup vs baseline: 1.1800x; 1.1800x over previous
//
#include <hip/hip_runtime.h>

typedef unsigned short u16;
typedef __attribute__((ext_vector_type(8))) short bf16x8;
typedef __attribute__((ext_vector_type(8))) unsigned short u16x8;
typedef __attribute__((ext_vector_type(4))) float f32x4;

#define N_NODES 10000
#define E_EDGES 160000
#define CX_N 2560000
#define W_N  65536
#define WB_N 4194304
// big canon total = CX_N + 4*W_N + WB_N = 7016448 elems = 877056 x8 = 3426 blocks
#define CANON_BIG_BLOCKS 3426
#define HIST_BLOCKS 79          // 79*2048 = 161792 >= E_EDGES

__device__ __forceinline__ float b2f(u16 u) {
  union { unsigned i; float f; } c; c.i = ((unsigned)u) << 16; return c.f;
}
__device__ __forceinline__ u16 f2b(float f) {
  union { float f; unsigned i; } c; c.f = f;
  unsigned i = c.i;
  return (u16)((i + 0x7FFFu + ((i >> 16) & 1u)) >> 16);  // RNE
}

// ---------------------------------------------------------------------------
// Dtype detection (bf16 vs f32 inputs), R2-verified.
// ---------------------------------------------------------------------------
__global__ void detect_kernel(const unsigned* __restrict__ w, int* __restrict__ flag) {
  int t = threadIdx.x;  // 64 threads
  int cnt = 0;
  for (int i = t; i < 1024; i += 64) {
    unsigned e = (w[i] >> 7) & 0xFF;
    cnt += (e >= 100 && e <= 145) ? 1 : 0;
  }
  for (int o = 32; o; o >>= 1) cnt += __shfl_xor(cnt, o);
  if (t == 0) *flag = (cnt >= 512) ? 1 : 0;
}

// ---------------------------------------------------------------------------
// canon_all (R13-verified, ~7 µs tail win): ONE launch = 4 canons + hist.
// ---------------------------------------------------------------------------
__global__ void canon_all_kernel(const void* sx, const void* swc, const void* sw1,
                                 const void* sw2, const void* sw4, const void* swB,
                                 const void* sbc, const void* sb1, const void* sb2,
                                 const void* sb4, const void* sw3, const void* sbB,
                                 const void* sb3,
                                 u16* __restrict__ dstBase,   // = cx (contiguous run)
                                 u16* cbc, u16* cb1, u16* cb2, u16* cb4,
                                 u16* cw3, u16* cbB, u16* cb3,
                                 const int* __restrict__ ei, int* __restrict__ count,
                                 const int* __restrict__ flag) {
  int b = blockIdx.x;
  int f = *flag;
  if (b < CANON_BIG_BLOCKS) {
    long e = ((long)b * 256 + threadIdx.x) * 8;   // elem offset (8-aligned)
    const void* src; long so;
    if (e < CX_N)                { src = sx;  so = e; }
    else if (e < CX_N + W_N)     { src = swc; so = e - CX_N; }
    else if (e < CX_N + 2 * W_N) { src = sw1; so = e - (CX_N + W_N); }
    else if (e < CX_N + 3 * W_N) { src = sw2; so = e - (CX_N + 2 * W_N); }
    else if (e < CX_N + 4 * W_N) { src = sw4; so = e - (CX_N + 3 * W_N); }
    else                         { src = swB; so = e - (CX_N + 4 * W_N); }
    if (f) {
      u16x8 v = *((const u16x8*)((const u16*)src + so));
      *(u16x8*)(dstBase + e) = v;
    } else {
      const float* fp = (const float*)src + so;
      float4 a = *(const float4*)fp;
      float4 c = *(const float4*)(fp + 4);
      u16x8 o;
      o[0] = f2b(a.x); o[1] = f2b(a.y); o[2] = f2b(a.z); o[3] = f2b(a.w);
      o[4] = f2b(c.x); o[5] = f2b(c.y); o[6] = f2b(c.z); o[7] = f2b(c.w);
      *(u16x8*)(dstBase + e) = o;
    }
  } else if (b == CANON_BIG_BLOCKS) {
    int t = threadIdx.x;
    const void* srcs[7] = {sbc, sb1, sb2, sb4, sw3, sbB, sb3};
    u16* dsts[7] = {cbc, cb1, cb2, cb4, cw3, cbB, cb3};
    const int ns[7] = {256, 256, 256, 256, 256, 64, 1};
#pragma unroll
    for (int k = 0; k < 7; ++k) {
      if (t < ns[k]) {
        if (f) dsts[k][t] = ((const u16*)srcs[k])[t];
        else   dsts[k][t] = f2b(((const float*)srcs[k])[t]);
      }
    }
  } else {
    int base = (b - CANON_BIG_BLOCKS - 1) * 2048 + threadIdx.x * 8;
#pragma unroll
    for (int k = 0; k < 8; ++k) {
      int i = base + k;
      if (i < E_EDGES) atomicAdd(&count[ei[E_EDGES + i]], 1);
    }
  }
}

// ---------------------------------------------------------------------------
// GEMM core (m97-style, R5/R12-verified): 128x128 tile, BK=64, 4 waves,
// global_load_lds 16B + XOR chunk swizzle (0 bank conflicts).
// (round-0 form — R14/R15 schedule edits regressed and are backed out)
// ---------------------------------------------------------------------------
__device__ __forceinline__ void stage_async(const u16* __restrict__ src, int stride,
                                            int row0, int maxRow, int k0,
                                            u16* lds, int w, int lane) {
  int rsel = lane >> 3;
  int gch = (lane & 7) ^ rsel;
#pragma unroll
  for (int i = 0; i < 4; ++i) {
    int rb = (w * 4 + i) * 8;
    int grow = row0 + rb + rsel;
    grow = grow > maxRow ? maxRow : grow;
    const u16* gp = src + (size_t)grow * stride + k0 + gch * 8;
    u16* lp = lds + rb * 64;
    __builtin_amdgcn_global_load_lds(
        (const __attribute__((address_space(1))) void*)gp,
        (__attribute__((address_space(3))) void*)lp, 16, 0, 0);
  }
}

__device__ __forceinline__ void mma_tile(const u16* lA, const u16* lB,
                                         f32x4 acc[4][4], int wr, int wc, int lane) {
#pragma unroll
  for (int ks = 0; ks < 2; ++ks) {
    bf16x8 af[4], bfr[4];
    int g = ks * 4 + (lane >> 4);
#pragma unroll
    for (int t = 0; t < 4; ++t) {
      int rowA = wr * 64 + t * 16 + (lane & 15);
      af[t] = *(const bf16x8*)(lA + rowA * 64 + ((g ^ (rowA & 7)) * 8));
      int rowB = wc * 64 + t * 16 + (lane & 15);
      bfr[t] = *(const bf16x8*)(lB + rowB * 64 + ((g ^ (rowB & 7)) * 8));
    }
#pragma unroll
    for (int ti = 0; ti < 4; ++ti)
#pragma unroll
      for (int tj = 0; tj < 4; ++tj)
        acc[ti][tj] = __builtin_amdgcn_mfma_f32_16x16x32_bf16(af[ti], bfr[tj],
                                                              acc[ti][tj], 0, 0, 0);
  }
}

template <bool RELU, bool F32OUT>
__global__ __launch_bounds__(256, 2)
void gemm_kernel(const u16* __restrict__ A, const u16* __restrict__ B,
                 const u16* __restrict__ bias, float* __restrict__ outF,
                 u16* __restrict__ outB, int NN, int J, int K) {
  __shared__ u16 lA[128 * 64];
  __shared__ u16 lB[128 * 64];
  int lane = threadIdx.x & 63;
  int w = threadIdx.x >> 6;
  int wr = w >> 1, wc = w & 1;
  int n0 = blockIdx.y * 128;
  int j0 = blockIdx.x * 128;
  f32x4 acc[4][4];
#pragma unroll
  for (int i = 0; i < 4; ++i)
#pragma unroll
    for (int j = 0; j < 4; ++j) acc[i][j] = (f32x4){0.f, 0.f, 0.f, 0.f};

  for (int kt = 0; kt < K; kt += 64) {
    stage_async(A, K, n0, NN - 1, kt, lA, w, lane);
    stage_async(B, K, j0, J - 1, kt, lB, w, lane);
    __syncthreads();
    mma_tile(lA, lB, acc, wr, wc, lane);
    __syncthreads();
  }

#pragma unroll
  for (int ti = 0; ti < 4; ++ti)
#pragma unroll
    for (int tj = 0; tj < 4; ++tj) {
      int col = j0 + wc * 64 + tj * 16 + (lane & 15);
      float bv = bias ? b2f(bias[col]) : 0.0f;
#pragma unroll
      for (int r = 0; r < 4; ++r) {
        int row = n0 + wr * 64 + ti * 16 + ((lane >> 4) << 2) + r;
        if (row < NN) {
          float v = acc[ti][tj][r] + bv;
          if (RELU) v = fmaxf(v, 0.0f);
          if (F32OUT) outF[(size_t)row * J + col] = v;
          else        outB[(size_t)row * J + col] = f2b(v);
        }
      }
    }
}

// ---------------------------------------------------------------------------
// Fused lin2+lin3+lin4 (R10-verified, round-0 form).
// ---------------------------------------------------------------------------
__global__ __launch_bounds__(256, 2)
void gemm_fused234_kernel(const u16* __restrict__ A, const u16* __restrict__ B,
                          const u16* __restrict__ bias, const u16* __restrict__ w3,
                          float* __restrict__ out1acc, u16* __restrict__ x2v, int NN) {
  __shared__ u16 lA[128 * 64];
  __shared__ u16 lB[128 * 64];
  int lane = threadIdx.x & 63;
  int w = threadIdx.x >> 6;
  int wr = w >> 1, wc = w & 1;
  int n0 = blockIdx.y * 128;
  int j0 = blockIdx.x * 128;
  f32x4 acc[4][4];
#pragma unroll
  for (int i = 0; i < 4; ++i)
#pragma unroll
    for (int j = 0; j < 4; ++j) acc[i][j] = (f32x4){0.f, 0.f, 0.f, 0.f};

  for (int kt = 0; kt < 256; kt += 64) {
    stage_async(A, 256, n0, NN - 1, kt, lA, w, lane);
    stage_async(B, 256, j0, 511, kt, lB, w, lane);
    __syncthreads();
    mma_tile(lA, lB, acc, wr, wc, lane);
    __syncthreads();
  }

  if (j0 < 256) {
    float part[4][4];
#pragma unroll
    for (int ti = 0; ti < 4; ++ti)
#pragma unroll
      for (int r = 0; r < 4; ++r) part[ti][r] = 0.0f;
#pragma unroll
    for (int ti = 0; ti < 4; ++ti)
#pragma unroll
      for (int tj = 0; tj < 4; ++tj) {
        int col = j0 + wc * 64 + tj * 16 + (lane & 15);
        float bv = b2f(bias[col]);
        float wv = b2f(w3[col]);
#pragma unroll
        for (int r = 0; r < 4; ++r) {
          float v = fmaxf(acc[ti][tj][r] + bv, 0.0f);
          part[ti][r] += v * wv;
        }
      }
#pragma unroll
    for (int ti = 0; ti < 4; ++ti)
#pragma unroll
      for (int r = 0; r < 4; ++r) {
        float s = part[ti][r];
        s += __shfl_xor(s, 1);
        s += __shfl_xor(s, 2);
        s += __shfl_xor(s, 4);
        s += __shfl_xor(s, 8);
        if ((lane & 15) == 0) {
          int row = n0 + wr * 64 + ti * 16 + ((lane >> 4) << 2) + r;
          if (row < NN) unsafeAtomicAdd(&out1acc[row], s);
        }
      }
  } else {
#pragma unroll
    for (int ti = 0; ti < 4; ++ti)
#pragma unroll
      for (int tj = 0; tj < 4; ++tj) {
        int col = j0 + wc * 64 + tj * 16 + (lane & 15);
        float bv = b2f(bias[col]);
#pragma unroll
        for (int r = 0; r < 4; ++r) {
          int row = n0 + wr * 64 + ti * 16 + ((lane >> 4) << 2) + r;
          if (row < NN) {
            float v = fmaxf(acc[ti][tj][r] + bv, 0.0f);
            x2v[(size_t)row * 256 + (col - 256)] = f2b(v);
          }
        }
      }
  }
}

// ---------------------------------------------------------------------------
// R18 bilinear: 8-phase 256x256 schedule (T3+T4+T5), rerun of R17 hardened:
// __launch_bounds__(512,1) — LDS (128 KB) already limits to 1 block/CU, so
// the (512,2) VGPR cap bought nothing and risked spill.
// BM=BN=256, BK=64, 512 thr / 8 waves (2Mx4N), per-wave 128x64, acc[8][4].
// K=256 = 4 K-tiles (T0..T3) in 2 LDS buffers (b0,b1,b0,b1; 128 KB total).
// Per K-tile: 4 quadrant phases {ds-read subtile; [stage next-next tile];
// s_barrier; setprio(1); 16 MFMA; setprio(0); s_barrier}. vmcnt gates ONLY
// at K-tile boundaries; gated loads were issued >=3 phases earlier so the
// wait is ~free. Prologue keeps T1's 8 loads in flight across all of T0
// (vmcnt(8) — true counted wait). Stage/read swizzle identical to the
// R13-verified pair; barrier/vmcnt/128KB-LDS primitives identical to the
// R15-passed ones. BN=256 = one full region -> epilogue dot is block-local.
// ---------------------------------------------------------------------------
__device__ __forceinline__ void stage512(const u16* __restrict__ src,
                                         int row0, int maxRow, int k0,
                                         u16* lds, int w, int lane) {
  int rsel = lane >> 3;            // row within 8-row group
  int gch = (lane & 7) ^ rsel;     // pre-swizzled source chunk
#pragma unroll
  for (int i = 0; i < 2; ++i) {
    int rb = (w * 2 + i) * 8;      // 16 groups of 8 rows / 8 waves
    int grow = row0 + rb + rsel;
    grow = grow > maxRow ? maxRow : grow;
    const u16* gp = src + (size_t)grow * 256 + k0 + gch * 8;
    u16* lp = lds + rb * 64;
    __builtin_amdgcn_global_load_lds(
        (const __attribute__((address_space(1))) void*)gp,
        (__attribute__((address_space(3))) void*)lp, 16, 0, 0);
  }
}

__device__ __forceinline__ void read_af(const u16* A, bf16x8 af[4][2],
                                        int qm, int wr, int lane) {
#pragma unroll
  for (int t = 0; t < 4; ++t)
#pragma unroll
    for (int ks = 0; ks < 2; ++ks) {
      int rowA = wr * 128 + (qm * 4 + t) * 16 + (lane & 15);
      int g = ks * 4 + (lane >> 4);
      af[t][ks] = *(const bf16x8*)(A + rowA * 64 + ((g ^ (rowA & 7)) * 8));
    }
}
__device__ __forceinline__ void read_bf(const u16* B, bf16x8 bf[2][2],
                                        int qn, int wc, int lane) {
#pragma unroll
  for (int u = 0; u < 2; ++u)
#pragma unroll
    for (int ks = 0; ks < 2; ++ks) {
      int rowB = wc * 64 + (qn * 2 + u) * 16 + (lane & 15);
      int g = ks * 4 + (lane >> 4);
      bf[u][ks] = *(const bf16x8*)(B + rowB * 64 + ((g ^ (rowB & 7)) * 8));
    }
}
__device__ __forceinline__ void mma16(f32x4 acc[8][4], bf16x8 af[4][2],
                                      bf16x8 bf[2][2], int qm, int qn) {
#pragma unroll
  for (int t = 0; t < 4; ++t)
#pragma unroll
    for (int u = 0; u < 2; ++u)
#pragma unroll
      for (int ks = 0; ks < 2; ++ks)
        acc[qm * 4 + t][qn * 2 + u] = __builtin_amdgcn_mfma_f32_16x16x32_bf16(
            af[t][ks], bf[u][ks], acc[qm * 4 + t][qn * 2 + u], 0, 0, 0);
}

#define BIL_BAR() asm volatile("s_barrier" ::: "memory")

__global__ __launch_bounds__(512, 1)
void bilinear8p_kernel(const u16* __restrict__ x2v, const u16* __restrict__ W,
                       float* __restrict__ out2acc, int NN) {
  __shared__ u16 lA[2][16384];   // [buf][256 rows x 64 cols]
  __shared__ u16 lB[2][16384];
  int lane = threadIdx.x & 63;
  int w = threadIdx.x >> 6;      // 0..7
  int wr = w >> 2, wc = w & 3;   // 2M x 4N
  int region = blockIdx.x;       // 0..63 (one full region per block)
  int n0 = blockIdx.y * 256;
  int rm0 = region * 256;

  f32x4 acc[8][4];
#pragma unroll
  for (int m = 0; m < 8; ++m)
#pragma unroll
    for (int n = 0; n < 4; ++n) acc[m][n] = (f32x4){0.f, 0.f, 0.f, 0.f};

  // prologue: T0 -> buf0, T1 -> buf1 (16 loads/thread total)
  stage512(x2v, n0,       NN - 1, 0,  &lA[0][0],    w, lane);
  stage512(x2v, n0 + 128, NN - 1, 0,  &lA[0][8192], w, lane);
  stage512(W,   rm0,       16383, 0,  &lB[0][0],    w, lane);
  stage512(W,   rm0 + 128, 16383, 0,  &lB[0][8192], w, lane);
  stage512(x2v, n0,       NN - 1, 64, &lA[1][0],    w, lane);
  stage512(x2v, n0 + 128, NN - 1, 64, &lA[1][8192], w, lane);
  stage512(W,   rm0,       16383, 64, &lB[1][0],    w, lane);
  stage512(W,   rm0 + 128, 16383, 64, &lB[1][8192], w, lane);
  asm volatile("s_waitcnt vmcnt(8)" ::: "memory");  // T0 ready; T1 in flight
  BIL_BAR();

#pragma unroll
  for (int kt = 0; kt < 4; ++kt) {
    const u16* A = lA[kt & 1];
    const u16* B = lB[kt & 1];
    bf16x8 af[4][2], bf0[2][2], bf1[2][2];
    // ---- phase 1: q(0,0); burst-stage K-tile kt+2 into the freed buffer
    read_af(A, af, 0, wr, lane);
    read_bf(B, bf0, 0, wc, lane);
    if (kt == 1) {          // T2 -> buf0 (freed by T0's ending barrier)
      stage512(x2v, n0,       NN - 1, 128, &lA[0][0],    w, lane);
      stage512(x2v, n0 + 128, NN - 1, 128, &lA[0][8192], w, lane);
      stage512(W,   rm0,       16383, 128, &lB[0][0],    w, lane);
      stage512(W,   rm0 + 128, 16383, 128, &lB[0][8192], w, lane);
    } else if (kt == 2) {   // T3 -> buf1
      stage512(x2v, n0,       NN - 1, 192, &lA[1][0],    w, lane);
      stage512(x2v, n0 + 128, NN - 1, 192, &lA[1][8192], w, lane);
      stage512(W,   rm0,       16383, 192, &lB[1][0],    w, lane);
      stage512(W,   rm0 + 128, 16383, 192, &lB[1][8192], w, lane);
    }
    BIL_BAR();
    __builtin_amdgcn_s_setprio(1);
    mma16(acc, af, bf0, 0, 0);
    __builtin_amdgcn_s_setprio(0);
    BIL_BAR();
    // ---- phase 2: q(0,1)
    read_bf(B, bf1, 1, wc, lane);
    BIL_BAR();
    __builtin_amdgcn_s_setprio(1);
    mma16(acc, af, bf1, 0, 1);
    __builtin_amdgcn_s_setprio(0);
    BIL_BAR();
    // ---- phase 3: q(1,0)
    read_af(A, af, 1, wr, lane);
    BIL_BAR();
    __builtin_amdgcn_s_setprio(1);
    mma16(acc, af, bf0, 1, 0);
    __builtin_amdgcn_s_setprio(0);
    BIL_BAR();
    // ---- phase 4: q(1,1); then K-tile gate (loads issued >=3 phases ago)
    __builtin_amdgcn_s_setprio(1);
    mma16(acc, af, bf1, 1, 1);
    __builtin_amdgcn_s_setprio(0);
    if (kt < 3) {
      asm volatile("s_waitcnt vmcnt(0)" ::: "memory");
      BIL_BAR();
    }
  }

  // epilogue: out2[row, region] = sum_i acc[row, i] * x2[row, i]
  // (i = this wave's wc-quarter of the 256 region rows; x2 re-read from L2)
#pragma unroll
  for (int mt = 0; mt < 8; ++mt)
#pragma unroll
    for (int r = 0; r < 4; ++r) {
      int row = n0 + wr * 128 + mt * 16 + ((lane >> 4) << 2) + r;
      int rc = row < NN ? row : NN - 1;
      const u16* xr = x2v + (size_t)rc * 256 + wc * 64 + (lane & 15);
      float s = 0.0f;
#pragma unroll
      for (int nt = 0; nt < 4; ++nt)
        s += acc[mt][nt][r] * b2f(xr[nt * 16]);
      s += __shfl_xor(s, 1);
      s += __shfl_xor(s, 2);
      s += __shfl_xor(s, 4);
      s += __shfl_xor(s, 8);
      if ((lane & 15) == 0 && row < NN)
        unsafeAtomicAdd(&out2acc[(size_t)row * 64 + region], s);
    }
}

// --------------------- edge sort (scan/place) + gather ----------------------
__global__ void scan_kernel(const int* __restrict__ count, int* __restrict__ start,
                            int* __restrict__ cursor, float* __restrict__ dinv) {
  __shared__ int wsum[16];
  __shared__ int carry_s;
  int t = threadIdx.x;          // 1024 threads = 16 waves
  int wv = t >> 6, ln = t & 63;
  if (t == 0) carry_s = 0;
  __syncthreads();
  for (int base = 0; base < N_NODES; base += 1024) {
    int i = base + t;
    int v = (i < N_NODES) ? count[i] : 0;
    int s = v;
#pragma unroll
    for (int o = 1; o < 64; o <<= 1) {
      int u = __shfl_up(s, o);
      if (ln >= o) s += u;
    }
    if (ln == 63) wsum[wv] = s;
    __syncthreads();
    if (wv == 0) {
      int x = (ln < 16) ? wsum[ln] : 0;
#pragma unroll
      for (int o = 1; o < 16; o <<= 1) {
        int u = __shfl_up(x, o);
        if (ln >= o) x += u;
      }
      if (ln < 16) wsum[ln] = x;
    }
    __syncthreads();
    int excl = s - v + (wv ? wsum[wv - 1] : 0) + carry_s;
    if (i < N_NODES) {
      start[i] = excl;
      cursor[i] = excl;
      dinv[i] = rsqrtf(1.0f + (float)v);
    }
    __syncthreads();
    if (t == 0) carry_s += wsum[15];
    __syncthreads();
  }
}

__global__ void place_kernel(const int* __restrict__ ei, int* __restrict__ cursor,
                             int* __restrict__ order) {
  int i = blockIdx.x * 256 + threadIdx.x;
  if (i >= E_EDGES) return;
  int d = ei[E_EDGES + i];
  int pos = atomicAdd(&cursor[d], 1);
  order[pos] = i;
}

__global__ void gather_kernel(const int* __restrict__ ei, const int* __restrict__ order,
                              const int* __restrict__ start, const int* __restrict__ count,
                              const float* __restrict__ dinv, const float* __restrict__ xw,
                              const u16* __restrict__ conv_b, const u16* __restrict__ x,
                              u16* __restrict__ x0) {
  int node = (blockIdx.x * blockDim.x + threadIdx.x) >> 6;
  int lane = threadIdx.x & 63;
  if (node >= N_NODES) return;
  int s0 = start[node], cnt = count[node];
  float dn = dinv[node];
  float ax = 0.f, ay = 0.f, az = 0.f, aw = 0.f;
  for (int base = 0; base < cnt; base += 64) {
    int rem = cnt - base;
    int m = rem < 64 ? rem : 64;
    int eid = (lane < m) ? order[s0 + base + lane] : 0;
    int s = (lane < m) ? ei[eid] : 0;
    float nrm = (lane < m) ? dinv[s] * dn : 0.f;
    for (int j = 0; j < m; ++j) {
      int sj = __shfl(s, j);
      float nj = __shfl(nrm, j);
      float4 v = *((const float4*)(xw + (size_t)sj * 256) + lane);
      ax += nj * v.x; ay += nj * v.y; az += nj * v.z; aw += nj * v.w;
    }
  }
  float4 sv = *((const float4*)(xw + (size_t)node * 256) + lane);
  float slw = dn * dn;
  const u16* bb = conv_b + lane * 4;
  const u16* xr = x + (size_t)node * 256 + lane * 4;
  u16 o[4];
  float vals[4] = {ax + slw * sv.x, ay + slw * sv.y, az + slw * sv.z, aw + slw * sv.w};
#pragma unroll
  for (int j = 0; j < 4; ++j) {
    float v = vals[j] + b2f(bb[j]);
    v = fmaxf(v, 0.0f) + b2f(xr[j]);
    o[j] = f2b(v);
  }
  *((ushort4*)(x0 + (size_t)node * 256) + lane) = make_ushort4(o[0], o[1], o[2], o[3]);
}

// ------------------------------- final output -------------------------------
__global__ void out_final_kernel(const float* __restrict__ out1acc,
                                 const float* __restrict__ out2acc,
                                 const u16* __restrict__ b3, const u16* __restrict__ bb,
                                 void* __restrict__ dout, const int* __restrict__ flag) {
  int idx = blockIdx.x * 256 + threadIdx.x;
  int f = *flag;
  if (idx < N_NODES) {
    float v = out1acc[idx] + b2f(b3[0]);
    if (f) ((u16*)dout)[idx] = f2b(v);
    else   ((float*)dout)[idx] = v;
  } else if (idx < N_NODES + N_NODES * 64) {
    int k = idx - N_NODES;
    float v = out2acc[k] + b2f(bb[k & 63]);
    if (f) ((u16*)dout)[idx] = f2b(v);
    else   ((float*)dout)[idx] = v;
  }
}

// ----------------------------------------------------------------------------
extern "C" void kernel_launch(void* const* d_in, const int* in_sizes, int n_in,
                              void* d_out, int out_size, void* d_ws, size_t ws_size,
                              hipStream_t stream) {
  const int* ei = (const int*)d_in[1];

  float* ws      = (float*)d_ws;
  float* xw      = ws;                          // [N,256] f32
  int*   count   = (int*)(xw + N_NODES * 256);  // [N]
  int*   start   = count + 10240;               // [N]
  int*   cursor  = start + 10240;               // [N]
  int*   order   = cursor + 10240;              // [E]
  float* dinv    = (float*)(order + E_EDGES);   // [N]
  float* out1acc = dinv + 10240;                // [N] (padded 10240)
  float* out2acc = out1acc + 10240;             // [N,64] (adjacent: one memset)
  u16* x0  = (u16*)(out2acc + N_NODES * 64);    // [N,256] bf16
  u16* x0m = x0 + N_NODES * 256;
  u16* x2v = x0m + N_NODES * 256;
  // canonical bf16 inputs — cx..cwB CONTIGUOUS (canon_all relies on this)
  u16* cx  = x2v + N_NODES * 256;
  u16* cwc = cx + CX_N;
  u16* cw1 = cwc + W_N;
  u16* cw2 = cw1 + W_N;                         // cw2, cw4 contiguous = [512,256]
  u16* cw4 = cw2 + W_N;
  u16* cwB = cw4 + W_N;
  u16* cbc = cwB + WB_N;
  u16* cb1 = cbc + 256;
  u16* cb2 = cb1 + 256;                         // cb2, cb4 contiguous = [512]
  u16* cb4 = cb2 + 256;
  u16* cw3 = cb4 + 256;
  u16* cbB = cw3 + 256;
  u16* cb3 = cbB + 64;
  int* flag = (int*)(cb3 + 16);

  hipMemsetAsync(count, 0, N_NODES * sizeof(int), stream);
  hipMemsetAsync(out1acc, 0, (10240 + (size_t)N_NODES * 64) * sizeof(float), stream);

  detect_kernel<<<1, 64, 0, stream>>>((const unsigned*)d_in[0], flag);

  canon_all_kernel<<<CANON_BIG_BLOCKS + 1 + HIST_BLOCKS, 256, 0, stream>>>(
      d_in[0], d_in[2], d_in[4], d_in[6], d_in[10], d_in[12],
      d_in[3], d_in[5], d_in[7], d_in[11], d_in[8], d_in[13], d_in[9],
      cx, cbc, cb1, cb2, cb4, cw3, cbB, cb3,
      ei, count, flag);

  scan_kernel<<<1, 1024, 0, stream>>>(count, start, cursor, dinv);
  place_kernel<<<(E_EDGES + 255) / 256, 256, 0, stream>>>(ei, cursor, order);

  gemm_kernel<false, true><<<dim3(2, 79), 256, 0, stream>>>(
      cx, cwc, nullptr, xw, nullptr, N_NODES, 256, 256);

  gather_kernel<<<(N_NODES * 64 + 255) / 256, 256, 0, stream>>>(
      ei, order, start, count, dinv, xw, cbc, cx, x0);

  gemm_kernel<true, false><<<dim3(2, 79), 256, 0, stream>>>(
      x0, cw1, cb1, nullptr, x0m, N_NODES, 256, 256);

  gemm_fused234_kernel<<<dim3(4, 79), 256, 0, stream>>>(
      x0m, cw2, cb2, cw3, out1acc, x2v, N_NODES);

  bilinear8p_kernel<<<dim3(64, 40), 512, 0, stream>>>(x2v, cwB, out2acc, N_NODES);

  out_final_kernel<<<(N_NODES * 65 + 255) / 256, 256, 0, stream>>>(
      out1acc, out2acc, cb3, cbB, d_out, flag);
}

// Round 6
// 386.843 us; speedup vs baseline: 1.4330x; 1.2144x over previous
//
#include <hip/hip_runtime.h>

typedef unsigned short u16;
typedef __attribute__((ext_vector_type(8))) short bf16x8;
typedef __attribute__((ext_vector_type(8))) unsigned short u16x8;
typedef __attribute__((ext_vector_type(4))) float f32x4;

#define N_NODES 10000
#define E_EDGES 160000
#define CX_N 2560000
#define W_N  65536
#define WB_N 4194304
// big canon total = CX_N + 4*W_N + WB_N = 7016448 elems = 877056 x8 = 3426 blocks
#define CANON_BIG_BLOCKS 3426
#define HIST_BLOCKS 79          // 79*2048 = 161792 >= E_EDGES

__device__ __forceinline__ float b2f(u16 u) {
  union { unsigned i; float f; } c; c.i = ((unsigned)u) << 16; return c.f;
}
__device__ __forceinline__ u16 f2b(float f) {
  union { float f; unsigned i; } c; c.f = f;
  unsigned i = c.i;
  return (u16)((i + 0x7FFFu + ((i >> 16) & 1u)) >> 16);  // RNE
}

// ---------------------------------------------------------------------------
// Dtype detection (bf16 vs f32 inputs), R2-verified.
// ---------------------------------------------------------------------------
__global__ void detect_kernel(const unsigned* __restrict__ w, int* __restrict__ flag) {
  int t = threadIdx.x;  // 64 threads
  int cnt = 0;
  for (int i = t; i < 1024; i += 64) {
    unsigned e = (w[i] >> 7) & 0xFF;
    cnt += (e >= 100 && e <= 145) ? 1 : 0;
  }
  for (int o = 32; o; o >>= 1) cnt += __shfl_xor(cnt, o);
  if (t == 0) *flag = (cnt >= 512) ? 1 : 0;
}

// ---------------------------------------------------------------------------
// canon_all (R13-verified, ~7 µs tail win): ONE launch = 4 canons + hist.
// ---------------------------------------------------------------------------
__global__ void canon_all_kernel(const void* sx, const void* swc, const void* sw1,
                                 const void* sw2, const void* sw4, const void* swB,
                                 const void* sbc, const void* sb1, const void* sb2,
                                 const void* sb4, const void* sw3, const void* sbB,
                                 const void* sb3,
                                 u16* __restrict__ dstBase,   // = cx (contiguous run)
                                 u16* cbc, u16* cb1, u16* cb2, u16* cb4,
                                 u16* cw3, u16* cbB, u16* cb3,
                                 const int* __restrict__ ei, int* __restrict__ count,
                                 const int* __restrict__ flag) {
  int b = blockIdx.x;
  int f = *flag;
  if (b < CANON_BIG_BLOCKS) {
    long e = ((long)b * 256 + threadIdx.x) * 8;   // elem offset (8-aligned)
    const void* src; long so;
    if (e < CX_N)                { src = sx;  so = e; }
    else if (e < CX_N + W_N)     { src = swc; so = e - CX_N; }
    else if (e < CX_N + 2 * W_N) { src = sw1; so = e - (CX_N + W_N); }
    else if (e < CX_N + 3 * W_N) { src = sw2; so = e - (CX_N + 2 * W_N); }
    else if (e < CX_N + 4 * W_N) { src = sw4; so = e - (CX_N + 3 * W_N); }
    else                         { src = swB; so = e - (CX_N + 4 * W_N); }
    if (f) {
      u16x8 v = *((const u16x8*)((const u16*)src + so));
      *(u16x8*)(dstBase + e) = v;
    } else {
      const float* fp = (const float*)src + so;
      float4 a = *(const float4*)fp;
      float4 c = *(const float4*)(fp + 4);
      u16x8 o;
      o[0] = f2b(a.x); o[1] = f2b(a.y); o[2] = f2b(a.z); o[3] = f2b(a.w);
      o[4] = f2b(c.x); o[5] = f2b(c.y); o[6] = f2b(c.z); o[7] = f2b(c.w);
      *(u16x8*)(dstBase + e) = o;
    }
  } else if (b == CANON_BIG_BLOCKS) {
    int t = threadIdx.x;
    const void* srcs[7] = {sbc, sb1, sb2, sb4, sw3, sbB, sb3};
    u16* dsts[7] = {cbc, cb1, cb2, cb4, cw3, cbB, cb3};
    const int ns[7] = {256, 256, 256, 256, 256, 64, 1};
#pragma unroll
    for (int k = 0; k < 7; ++k) {
      if (t < ns[k]) {
        if (f) dsts[k][t] = ((const u16*)srcs[k])[t];
        else   dsts[k][t] = f2b(((const float*)srcs[k])[t]);
      }
    }
  } else {
    int base = (b - CANON_BIG_BLOCKS - 1) * 2048 + threadIdx.x * 8;
#pragma unroll
    for (int k = 0; k < 8; ++k) {
      int i = base + k;
      if (i < E_EDGES) atomicAdd(&count[ei[E_EDGES + i]], 1);
    }
  }
}

// ---------------------------------------------------------------------------
// GEMM core (m97-style, R5/R12-verified): 128x128 tile, BK=64, 4 waves,
// global_load_lds 16B + XOR chunk swizzle (0 bank conflicts).
// ---------------------------------------------------------------------------
__device__ __forceinline__ void stage_async(const u16* __restrict__ src, int stride,
                                            int row0, int maxRow, int k0,
                                            u16* lds, int w, int lane) {
  int rsel = lane >> 3;
  int gch = (lane & 7) ^ rsel;
#pragma unroll
  for (int i = 0; i < 4; ++i) {
    int rb = (w * 4 + i) * 8;
    int grow = row0 + rb + rsel;
    grow = grow > maxRow ? maxRow : grow;
    const u16* gp = src + (size_t)grow * stride + k0 + gch * 8;
    u16* lp = lds + rb * 64;
    __builtin_amdgcn_global_load_lds(
        (const __attribute__((address_space(1))) void*)gp,
        (__attribute__((address_space(3))) void*)lp, 16, 0, 0);
  }
}

__device__ __forceinline__ void mma_tile(const u16* lA, const u16* lB,
                                         f32x4 acc[4][4], int wr, int wc, int lane) {
#pragma unroll
  for (int ks = 0; ks < 2; ++ks) {
    bf16x8 af[4], bfr[4];
    int g = ks * 4 + (lane >> 4);
#pragma unroll
    for (int t = 0; t < 4; ++t) {
      int rowA = wr * 64 + t * 16 + (lane & 15);
      af[t] = *(const bf16x8*)(lA + rowA * 64 + ((g ^ (rowA & 7)) * 8));
      int rowB = wc * 64 + t * 16 + (lane & 15);
      bfr[t] = *(const bf16x8*)(lB + rowB * 64 + ((g ^ (rowB & 7)) * 8));
    }
#pragma unroll
    for (int ti = 0; ti < 4; ++ti)
#pragma unroll
      for (int tj = 0; tj < 4; ++tj)
        acc[ti][tj] = __builtin_amdgcn_mfma_f32_16x16x32_bf16(af[ti], bfr[tj],
                                                              acc[ti][tj], 0, 0, 0);
  }
}

template <bool RELU, bool F32OUT>
__global__ __launch_bounds__(256, 2)
void gemm_kernel(const u16* __restrict__ A, const u16* __restrict__ B,
                 const u16* __restrict__ bias, float* __restrict__ outF,
                 u16* __restrict__ outB, int NN, int J, int K) {
  __shared__ u16 lA[128 * 64];
  __shared__ u16 lB[128 * 64];
  int lane = threadIdx.x & 63;
  int w = threadIdx.x >> 6;
  int wr = w >> 1, wc = w & 1;
  int n0 = blockIdx.y * 128;
  int j0 = blockIdx.x * 128;
  f32x4 acc[4][4];
#pragma unroll
  for (int i = 0; i < 4; ++i)
#pragma unroll
    for (int j = 0; j < 4; ++j) acc[i][j] = (f32x4){0.f, 0.f, 0.f, 0.f};

  for (int kt = 0; kt < K; kt += 64) {
    stage_async(A, K, n0, NN - 1, kt, lA, w, lane);
    stage_async(B, K, j0, J - 1, kt, lB, w, lane);
    __syncthreads();
    mma_tile(lA, lB, acc, wr, wc, lane);
    __syncthreads();
  }

#pragma unroll
  for (int ti = 0; ti < 4; ++ti)
#pragma unroll
    for (int tj = 0; tj < 4; ++tj) {
      int col = j0 + wc * 64 + tj * 16 + (lane & 15);
      float bv = bias ? b2f(bias[col]) : 0.0f;
#pragma unroll
      for (int r = 0; r < 4; ++r) {
        int row = n0 + wr * 64 + ti * 16 + ((lane >> 4) << 2) + r;
        if (row < NN) {
          float v = acc[ti][tj][r] + bv;
          if (RELU) v = fmaxf(v, 0.0f);
          if (F32OUT) outF[(size_t)row * J + col] = v;
          else        outB[(size_t)row * J + col] = f2b(v);
        }
      }
    }
}

// ---------------------------------------------------------------------------
// Fused lin2+lin3+lin4 (R10-verified, round-0 form).
// ---------------------------------------------------------------------------
__global__ __launch_bounds__(256, 2)
void gemm_fused234_kernel(const u16* __restrict__ A, const u16* __restrict__ B,
                          const u16* __restrict__ bias, const u16* __restrict__ w3,
                          float* __restrict__ out1acc, u16* __restrict__ x2v, int NN) {
  __shared__ u16 lA[128 * 64];
  __shared__ u16 lB[128 * 64];
  int lane = threadIdx.x & 63;
  int w = threadIdx.x >> 6;
  int wr = w >> 1, wc = w & 1;
  int n0 = blockIdx.y * 128;
  int j0 = blockIdx.x * 128;
  f32x4 acc[4][4];
#pragma unroll
  for (int i = 0; i < 4; ++i)
#pragma unroll
    for (int j = 0; j < 4; ++j) acc[i][j] = (f32x4){0.f, 0.f, 0.f, 0.f};

  for (int kt = 0; kt < 256; kt += 64) {
    stage_async(A, 256, n0, NN - 1, kt, lA, w, lane);
    stage_async(B, 256, j0, 511, kt, lB, w, lane);
    __syncthreads();
    mma_tile(lA, lB, acc, wr, wc, lane);
    __syncthreads();
  }

  if (j0 < 256) {
    float part[4][4];
#pragma unroll
    for (int ti = 0; ti < 4; ++ti)
#pragma unroll
      for (int r = 0; r < 4; ++r) part[ti][r] = 0.0f;
#pragma unroll
    for (int ti = 0; ti < 4; ++ti)
#pragma unroll
      for (int tj = 0; tj < 4; ++tj) {
        int col = j0 + wc * 64 + tj * 16 + (lane & 15);
        float bv = b2f(bias[col]);
        float wv = b2f(w3[col]);
#pragma unroll
        for (int r = 0; r < 4; ++r) {
          float v = fmaxf(acc[ti][tj][r] + bv, 0.0f);
          part[ti][r] += v * wv;
        }
      }
#pragma unroll
    for (int ti = 0; ti < 4; ++ti)
#pragma unroll
      for (int r = 0; r < 4; ++r) {
        float s = part[ti][r];
        s += __shfl_xor(s, 1);
        s += __shfl_xor(s, 2);
        s += __shfl_xor(s, 4);
        s += __shfl_xor(s, 8);
        if ((lane & 15) == 0) {
          int row = n0 + wr * 64 + ti * 16 + ((lane >> 4) << 2) + r;
          if (row < NN) unsafeAtomicAdd(&out1acc[row], s);
        }
      }
  } else {
#pragma unroll
    for (int ti = 0; ti < 4; ++ti)
#pragma unroll
      for (int tj = 0; tj < 4; ++tj) {
        int col = j0 + wc * 64 + tj * 16 + (lane & 15);
        float bv = b2f(bias[col]);
#pragma unroll
        for (int r = 0; r < 4; ++r) {
          int row = n0 + wr * 64 + ti * 16 + ((lane >> 4) << 2) + r;
          if (row < NN) {
            float v = fmaxf(acc[ti][tj][r] + bv, 0.0f);
            x2v[(size_t)row * 256 + (col - 256)] = f2b(v);
          }
        }
      }
  }
}

// ---------------------------------------------------------------------------
// Bilinear (R19): R13 kernel body VERBATIM — only the block->work mapping
// changed. Theory: R13-R18 were all L3-BW-bound streaming W (8.4 MB > 4 MB
// per-XCD L2): old grid re-streamed full W per n-tile round = 79 x 8.4 MB
// ~ 663 MB from L3 (~3.3 TB/s sustained = the plateau; FETCH stayed 24 MB
// because L3 absorbs it). New mapping (T1): each XCD owns a 16-W-tile
// stripe (1 MB, stays L2-resident) and sweeps n-tiles through it:
//   xcd = wgid & 7 (HW round-robin), nt = (wgid>>3)/16, wt = xcd*16 + (wgid>>3)%16
// Per-XCD L3 traffic: W 1 MB + x2 5 MB once ~ 50 MB total (13x less).
// 10112 % 8 == 0 -> bijective.
// ---------------------------------------------------------------------------
__global__ __launch_bounds__(256, 2)
void bilinear_kernel(const u16* __restrict__ x2v, const u16* __restrict__ W,
                     float* __restrict__ out2acc, int NN) {
  __shared__ u16 lA[128 * 64];
  __shared__ u16 lB[128 * 64];
  int lane = threadIdx.x & 63;
  int w = threadIdx.x >> 6;
  int wr = w >> 1, wc = w & 1;
  // XCD-stripe mapping (see header comment)
  int wgid = blockIdx.x;           // 0..10111
  int xcd = wgid & 7;
  int idx = wgid >> 3;             // 0..1263
  int nt = idx >> 4;               // 0..78  (n-tile, sweeps slowly)
  int wtl = idx & 15;              // 0..15  (W-tile within this XCD's stripe)
  int wt = xcd * 16 + wtl;         // 0..127
  int n0 = nt * 128;
  int rm0 = wt * 128;
  int m0g = rm0 & 255;
  int xv_kt = (m0g >> 6) + wc;
  f32x4 acc[4][4];
#pragma unroll
  for (int i = 0; i < 4; ++i)
#pragma unroll
    for (int j = 0; j < 4; ++j) acc[i][j] = (f32x4){0.f, 0.f, 0.f, 0.f};

  u16 xvr[4][16];

#pragma unroll
  for (int kt4 = 0; kt4 < 4; ++kt4) {
    stage_async(x2v, 256, n0, NN - 1, kt4 * 64, lA, w, lane);
    stage_async(W, 256, rm0, 16383, kt4 * 64, lB, w, lane);
    __syncthreads();
    mma_tile(lA, lB, acc, wr, wc, lane);
    if (kt4 == xv_kt) {
#pragma unroll
      for (int tj = 0; tj < 4; ++tj) {
        int kl = tj * 16 + (lane & 15);
        int ch = kl >> 3, off = kl & 7;
#pragma unroll
        for (int ti = 0; ti < 4; ++ti)
#pragma unroll
          for (int r = 0; r < 4; ++r) {
            int rowl = wr * 64 + ti * 16 + ((lane >> 4) << 2) + r;
            xvr[tj][ti * 4 + r] = lA[rowl * 64 + ((ch ^ (rowl & 7)) * 8) + off];
          }
      }
    }
    __syncthreads();
  }

  int region = rm0 >> 8;
  float rowsum[4][4];
#pragma unroll
  for (int ti = 0; ti < 4; ++ti)
#pragma unroll
    for (int r = 0; r < 4; ++r) rowsum[ti][r] = 0.0f;

#pragma unroll
  for (int ti = 0; ti < 4; ++ti)
#pragma unroll
    for (int tj = 0; tj < 4; ++tj)
#pragma unroll
      for (int r = 0; r < 4; ++r)
        rowsum[ti][r] += acc[ti][tj][r] * b2f(xvr[tj][ti * 4 + r]);

#pragma unroll
  for (int ti = 0; ti < 4; ++ti)
#pragma unroll
    for (int r = 0; r < 4; ++r) {
      float s = rowsum[ti][r];
      s += __shfl_xor(s, 1);
      s += __shfl_xor(s, 2);
      s += __shfl_xor(s, 4);
      s += __shfl_xor(s, 8);
      if ((lane & 15) == 0) {
        int rowl = wr * 64 + ti * 16 + ((lane >> 4) << 2) + r;
        int n = n0 + rowl;
        if (n < NN) unsafeAtomicAdd(&out2acc[(size_t)n * 64 + region], s);
      }
    }
}

// --------------------- edge sort (scan/place) + gather ----------------------
__global__ void scan_kernel(const int* __restrict__ count, int* __restrict__ start,
                            int* __restrict__ cursor, float* __restrict__ dinv) {
  __shared__ int wsum[16];
  __shared__ int carry_s;
  int t = threadIdx.x;          // 1024 threads = 16 waves
  int wv = t >> 6, ln = t & 63;
  if (t == 0) carry_s = 0;
  __syncthreads();
  for (int base = 0; base < N_NODES; base += 1024) {
    int i = base + t;
    int v = (i < N_NODES) ? count[i] : 0;
    int s = v;
#pragma unroll
    for (int o = 1; o < 64; o <<= 1) {
      int u = __shfl_up(s, o);
      if (ln >= o) s += u;
    }
    if (ln == 63) wsum[wv] = s;
    __syncthreads();
    if (wv == 0) {
      int x = (ln < 16) ? wsum[ln] : 0;
#pragma unroll
      for (int o = 1; o < 16; o <<= 1) {
        int u = __shfl_up(x, o);
        if (ln >= o) x += u;
      }
      if (ln < 16) wsum[ln] = x;
    }
    __syncthreads();
    int excl = s - v + (wv ? wsum[wv - 1] : 0) + carry_s;
    if (i < N_NODES) {
      start[i] = excl;
      cursor[i] = excl;
      dinv[i] = rsqrtf(1.0f + (float)v);
    }
    __syncthreads();
    if (t == 0) carry_s += wsum[15];
    __syncthreads();
  }
}

__global__ void place_kernel(const int* __restrict__ ei, int* __restrict__ cursor,
                             int* __restrict__ order) {
  int i = blockIdx.x * 256 + threadIdx.x;
  if (i >= E_EDGES) return;
  int d = ei[E_EDGES + i];
  int pos = atomicAdd(&cursor[d], 1);
  order[pos] = i;
}

__global__ void gather_kernel(const int* __restrict__ ei, const int* __restrict__ order,
                              const int* __restrict__ start, const int* __restrict__ count,
                              const float* __restrict__ dinv, const float* __restrict__ xw,
                              const u16* __restrict__ conv_b, const u16* __restrict__ x,
                              u16* __restrict__ x0) {
  int node = (blockIdx.x * blockDim.x + threadIdx.x) >> 6;
  int lane = threadIdx.x & 63;
  if (node >= N_NODES) return;
  int s0 = start[node], cnt = count[node];
  float dn = dinv[node];
  float ax = 0.f, ay = 0.f, az = 0.f, aw = 0.f;
  for (int base = 0; base < cnt; base += 64) {
    int rem = cnt - base;
    int m = rem < 64 ? rem : 64;
    int eid = (lane < m) ? order[s0 + base + lane] : 0;
    int s = (lane < m) ? ei[eid] : 0;
    float nrm = (lane < m) ? dinv[s] * dn : 0.f;
    for (int j = 0; j < m; ++j) {
      int sj = __shfl(s, j);
      float nj = __shfl(nrm, j);
      float4 v = *((const float4*)(xw + (size_t)sj * 256) + lane);
      ax += nj * v.x; ay += nj * v.y; az += nj * v.z; aw += nj * v.w;
    }
  }
  float4 sv = *((const float4*)(xw + (size_t)node * 256) + lane);
  float slw = dn * dn;
  const u16* bb = conv_b + lane * 4;
  const u16* xr = x + (size_t)node * 256 + lane * 4;
  u16 o[4];
  float vals[4] = {ax + slw * sv.x, ay + slw * sv.y, az + slw * sv.z, aw + slw * sv.w};
#pragma unroll
  for (int j = 0; j < 4; ++j) {
    float v = vals[j] + b2f(bb[j]);
    v = fmaxf(v, 0.0f) + b2f(xr[j]);
    o[j] = f2b(v);
  }
  *((ushort4*)(x0 + (size_t)node * 256) + lane) = make_ushort4(o[0], o[1], o[2], o[3]);
}

// ------------------------------- final output -------------------------------
__global__ void out_final_kernel(const float* __restrict__ out1acc,
                                 const float* __restrict__ out2acc,
                                 const u16* __restrict__ b3, const u16* __restrict__ bb,
                                 void* __restrict__ dout, const int* __restrict__ flag) {
  int idx = blockIdx.x * 256 + threadIdx.x;
  int f = *flag;
  if (idx < N_NODES) {
    float v = out1acc[idx] + b2f(b3[0]);
    if (f) ((u16*)dout)[idx] = f2b(v);
    else   ((float*)dout)[idx] = v;
  } else if (idx < N_NODES + N_NODES * 64) {
    int k = idx - N_NODES;
    float v = out2acc[k] + b2f(bb[k & 63]);
    if (f) ((u16*)dout)[idx] = f2b(v);
    else   ((float*)dout)[idx] = v;
  }
}

// ----------------------------------------------------------------------------
extern "C" void kernel_launch(void* const* d_in, const int* in_sizes, int n_in,
                              void* d_out, int out_size, void* d_ws, size_t ws_size,
                              hipStream_t stream) {
  const int* ei = (const int*)d_in[1];

  float* ws      = (float*)d_ws;
  float* xw      = ws;                          // [N,256] f32
  int*   count   = (int*)(xw + N_NODES * 256);  // [N]
  int*   start   = count + 10240;               // [N]
  int*   cursor  = start + 10240;               // [N]
  int*   order   = cursor + 10240;              // [E]
  float* dinv    = (float*)(order + E_EDGES);   // [N]
  float* out1acc = dinv + 10240;                // [N] (padded 10240)
  float* out2acc = out1acc + 10240;             // [N,64] (adjacent: one memset)
  u16* x0  = (u16*)(out2acc + N_NODES * 64);    // [N,256] bf16
  u16* x0m = x0 + N_NODES * 256;
  u16* x2v = x0m + N_NODES * 256;
  // canonical bf16 inputs — cx..cwB CONTIGUOUS (canon_all relies on this)
  u16* cx  = x2v + N_NODES * 256;
  u16* cwc = cx + CX_N;
  u16* cw1 = cwc + W_N;
  u16* cw2 = cw1 + W_N;                         // cw2, cw4 contiguous = [512,256]
  u16* cw4 = cw2 + W_N;
  u16* cwB = cw4 + W_N;
  u16* cbc = cwB + WB_N;
  u16* cb1 = cbc + 256;
  u16* cb2 = cb1 + 256;                         // cb2, cb4 contiguous = [512]
  u16* cb4 = cb2 + 256;
  u16* cw3 = cb4 + 256;
  u16* cbB = cw3 + 256;
  u16* cb3 = cbB + 64;
  int* flag = (int*)(cb3 + 16);

  hipMemsetAsync(count, 0, N_NODES * sizeof(int), stream);
  hipMemsetAsync(out1acc, 0, (10240 + (size_t)N_NODES * 64) * sizeof(float), stream);

  detect_kernel<<<1, 64, 0, stream>>>((const unsigned*)d_in[0], flag);

  canon_all_kernel<<<CANON_BIG_BLOCKS + 1 + HIST_BLOCKS, 256, 0, stream>>>(
      d_in[0], d_in[2], d_in[4], d_in[6], d_in[10], d_in[12],
      d_in[3], d_in[5], d_in[7], d_in[11], d_in[8], d_in[13], d_in[9],
      cx, cbc, cb1, cb2, cb4, cw3, cbB, cb3,
      ei, count, flag);

  scan_kernel<<<1, 1024, 0, stream>>>(count, start, cursor, dinv);
  place_kernel<<<(E_EDGES + 255) / 256, 256, 0, stream>>>(ei, cursor, order);

  gemm_kernel<false, true><<<dim3(2, 79), 256, 0, stream>>>(
      cx, cwc, nullptr, xw, nullptr, N_NODES, 256, 256);

  gather_kernel<<<(N_NODES * 64 + 255) / 256, 256, 0, stream>>>(
      ei, order, start, count, dinv, xw, cbc, cx, x0);

  gemm_kernel<true, false><<<dim3(2, 79), 256, 0, stream>>>(
      x0, cw1, cb1, nullptr, x0m, N_NODES, 256, 256);

  gemm_fused234_kernel<<<dim3(4, 79), 256, 0, stream>>>(
      x0m, cw2, cb2, cw3, out1acc, x2v, N_NODES);

  bilinear_kernel<<<dim3(10112), 256, 0, stream>>>(x2v, cwB, out2acc, N_NODES);

  out_final_kernel<<<(N_NODES * 65 + 255) / 256, 256, 0, stream>>>(
      out1acc, out2acc, cb3, cbB, d_out, flag);
}

// Round 7
// 367.346 us; speedup vs baseline: 1.5091x; 1.0531x over previous
//
#include <hip/hip_runtime.h>

typedef unsigned short u16;
typedef __attribute__((ext_vector_type(8))) short bf16x8;
typedef __attribute__((ext_vector_type(8))) unsigned short u16x8;
typedef __attribute__((ext_vector_type(4))) float f32x4;

#define N_NODES 10000
#define E_EDGES 160000
#define CX_N 2560000
#define W_N  65536
#define WB_N 4194304
// big canon total = CX_N + 4*W_N + WB_N = 7016448 elems = 877056 x8 = 3426 blocks
#define CANON_BIG_BLOCKS 3426
#define HIST_BLOCKS 79          // 79*2048 = 161792 >= E_EDGES

__device__ __forceinline__ float b2f(u16 u) {
  union { unsigned i; float f; } c; c.i = ((unsigned)u) << 16; return c.f;
}
__device__ __forceinline__ u16 f2b(float f) {
  union { float f; unsigned i; } c; c.f = f;
  unsigned i = c.i;
  return (u16)((i + 0x7FFFu + ((i >> 16) & 1u)) >> 16);  // RNE
}

// ---------------------------------------------------------------------------
// Dtype detection (bf16 vs f32 inputs), R2-verified.
// ---------------------------------------------------------------------------
__global__ void detect_kernel(const unsigned* __restrict__ w, int* __restrict__ flag) {
  int t = threadIdx.x;  // 64 threads
  int cnt = 0;
  for (int i = t; i < 1024; i += 64) {
    unsigned e = (w[i] >> 7) & 0xFF;
    cnt += (e >= 100 && e <= 145) ? 1 : 0;
  }
  for (int o = 32; o; o >>= 1) cnt += __shfl_xor(cnt, o);
  if (t == 0) *flag = (cnt >= 512) ? 1 : 0;
}

// ---------------------------------------------------------------------------
// canon_all (R13-verified, ~7 µs tail win): ONE launch = 4 canons + hist.
// ---------------------------------------------------------------------------
__global__ void canon_all_kernel(const void* sx, const void* swc, const void* sw1,
                                 const void* sw2, const void* sw4, const void* swB,
                                 const void* sbc, const void* sb1, const void* sb2,
                                 const void* sb4, const void* sw3, const void* sbB,
                                 const void* sb3,
                                 u16* __restrict__ dstBase,   // = cx (contiguous run)
                                 u16* cbc, u16* cb1, u16* cb2, u16* cb4,
                                 u16* cw3, u16* cbB, u16* cb3,
                                 const int* __restrict__ ei, int* __restrict__ count,
                                 const int* __restrict__ flag) {
  int b = blockIdx.x;
  int f = *flag;
  if (b < CANON_BIG_BLOCKS) {
    long e = ((long)b * 256 + threadIdx.x) * 8;   // elem offset (8-aligned)
    const void* src; long so;
    if (e < CX_N)                { src = sx;  so = e; }
    else if (e < CX_N + W_N)     { src = swc; so = e - CX_N; }
    else if (e < CX_N + 2 * W_N) { src = sw1; so = e - (CX_N + W_N); }
    else if (e < CX_N + 3 * W_N) { src = sw2; so = e - (CX_N + 2 * W_N); }
    else if (e < CX_N + 4 * W_N) { src = sw4; so = e - (CX_N + 3 * W_N); }
    else                         { src = swB; so = e - (CX_N + 4 * W_N); }
    if (f) {
      u16x8 v = *((const u16x8*)((const u16*)src + so));
      *(u16x8*)(dstBase + e) = v;
    } else {
      const float* fp = (const float*)src + so;
      float4 a = *(const float4*)fp;
      float4 c = *(const float4*)(fp + 4);
      u16x8 o;
      o[0] = f2b(a.x); o[1] = f2b(a.y); o[2] = f2b(a.z); o[3] = f2b(a.w);
      o[4] = f2b(c.x); o[5] = f2b(c.y); o[6] = f2b(c.z); o[7] = f2b(c.w);
      *(u16x8*)(dstBase + e) = o;
    }
  } else if (b == CANON_BIG_BLOCKS) {
    int t = threadIdx.x;
    const void* srcs[7] = {sbc, sb1, sb2, sb4, sw3, sbB, sb3};
    u16* dsts[7] = {cbc, cb1, cb2, cb4, cw3, cbB, cb3};
    const int ns[7] = {256, 256, 256, 256, 256, 64, 1};
#pragma unroll
    for (int k = 0; k < 7; ++k) {
      if (t < ns[k]) {
        if (f) dsts[k][t] = ((const u16*)srcs[k])[t];
        else   dsts[k][t] = f2b(((const float*)srcs[k])[t]);
      }
    }
  } else {
    int base = (b - CANON_BIG_BLOCKS - 1) * 2048 + threadIdx.x * 8;
#pragma unroll
    for (int k = 0; k < 8; ++k) {
      int i = base + k;
      if (i < E_EDGES) atomicAdd(&count[ei[E_EDGES + i]], 1);
    }
  }
}

// ---------------------------------------------------------------------------
// GEMM core (m97-style, R5/R12-verified): 128x128 tile, BK=64, 4 waves,
// global_load_lds 16B + XOR chunk swizzle (0 bank conflicts).
// ---------------------------------------------------------------------------
__device__ __forceinline__ void stage_async(const u16* __restrict__ src, int stride,
                                            int row0, int maxRow, int k0,
                                            u16* lds, int w, int lane) {
  int rsel = lane >> 3;
  int gch = (lane & 7) ^ rsel;
#pragma unroll
  for (int i = 0; i < 4; ++i) {
    int rb = (w * 4 + i) * 8;
    int grow = row0 + rb + rsel;
    grow = grow > maxRow ? maxRow : grow;
    const u16* gp = src + (size_t)grow * stride + k0 + gch * 8;
    u16* lp = lds + rb * 64;
    __builtin_amdgcn_global_load_lds(
        (const __attribute__((address_space(1))) void*)gp,
        (__attribute__((address_space(3))) void*)lp, 16, 0, 0);
  }
}

__device__ __forceinline__ void mma_tile(const u16* lA, const u16* lB,
                                         f32x4 acc[4][4], int wr, int wc, int lane) {
#pragma unroll
  for (int ks = 0; ks < 2; ++ks) {
    bf16x8 af[4], bfr[4];
    int g = ks * 4 + (lane >> 4);
#pragma unroll
    for (int t = 0; t < 4; ++t) {
      int rowA = wr * 64 + t * 16 + (lane & 15);
      af[t] = *(const bf16x8*)(lA + rowA * 64 + ((g ^ (rowA & 7)) * 8));
      int rowB = wc * 64 + t * 16 + (lane & 15);
      bfr[t] = *(const bf16x8*)(lB + rowB * 64 + ((g ^ (rowB & 7)) * 8));
    }
#pragma unroll
    for (int ti = 0; ti < 4; ++ti)
#pragma unroll
      for (int tj = 0; tj < 4; ++tj)
        acc[ti][tj] = __builtin_amdgcn_mfma_f32_16x16x32_bf16(af[ti], bfr[tj],
                                                              acc[ti][tj], 0, 0, 0);
  }
}

template <bool RELU, bool F32OUT>
__global__ __launch_bounds__(256, 2)
void gemm_kernel(const u16* __restrict__ A, const u16* __restrict__ B,
                 const u16* __restrict__ bias, float* __restrict__ outF,
                 u16* __restrict__ outB, int NN, int J, int K) {
  __shared__ u16 lA[128 * 64];
  __shared__ u16 lB[128 * 64];
  int lane = threadIdx.x & 63;
  int w = threadIdx.x >> 6;
  int wr = w >> 1, wc = w & 1;
  int n0 = blockIdx.y * 128;
  int j0 = blockIdx.x * 128;
  f32x4 acc[4][4];
#pragma unroll
  for (int i = 0; i < 4; ++i)
#pragma unroll
    for (int j = 0; j < 4; ++j) acc[i][j] = (f32x4){0.f, 0.f, 0.f, 0.f};

  for (int kt = 0; kt < K; kt += 64) {
    stage_async(A, K, n0, NN - 1, kt, lA, w, lane);
    stage_async(B, K, j0, J - 1, kt, lB, w, lane);
    __syncthreads();
    mma_tile(lA, lB, acc, wr, wc, lane);
    __syncthreads();
  }

#pragma unroll
  for (int ti = 0; ti < 4; ++ti)
#pragma unroll
    for (int tj = 0; tj < 4; ++tj) {
      int col = j0 + wc * 64 + tj * 16 + (lane & 15);
      float bv = bias ? b2f(bias[col]) : 0.0f;
#pragma unroll
      for (int r = 0; r < 4; ++r) {
        int row = n0 + wr * 64 + ti * 16 + ((lane >> 4) << 2) + r;
        if (row < NN) {
          float v = acc[ti][tj][r] + bv;
          if (RELU) v = fmaxf(v, 0.0f);
          if (F32OUT) outF[(size_t)row * J + col] = v;
          else        outB[(size_t)row * J + col] = f2b(v);
        }
      }
    }
}

// ---------------------------------------------------------------------------
// Fused lin2+lin3+lin4 (R10-verified, round-0 form).
// ---------------------------------------------------------------------------
__global__ __launch_bounds__(256, 2)
void gemm_fused234_kernel(const u16* __restrict__ A, const u16* __restrict__ B,
                          const u16* __restrict__ bias, const u16* __restrict__ w3,
                          float* __restrict__ out1acc, u16* __restrict__ x2v, int NN) {
  __shared__ u16 lA[128 * 64];
  __shared__ u16 lB[128 * 64];
  int lane = threadIdx.x & 63;
  int w = threadIdx.x >> 6;
  int wr = w >> 1, wc = w & 1;
  int n0 = blockIdx.y * 128;
  int j0 = blockIdx.x * 128;
  f32x4 acc[4][4];
#pragma unroll
  for (int i = 0; i < 4; ++i)
#pragma unroll
    for (int j = 0; j < 4; ++j) acc[i][j] = (f32x4){0.f, 0.f, 0.f, 0.f};

  for (int kt = 0; kt < 256; kt += 64) {
    stage_async(A, 256, n0, NN - 1, kt, lA, w, lane);
    stage_async(B, 256, j0, 511, kt, lB, w, lane);
    __syncthreads();
    mma_tile(lA, lB, acc, wr, wc, lane);
    __syncthreads();
  }

  if (j0 < 256) {
    float part[4][4];
#pragma unroll
    for (int ti = 0; ti < 4; ++ti)
#pragma unroll
      for (int r = 0; r < 4; ++r) part[ti][r] = 0.0f;
#pragma unroll
    for (int ti = 0; ti < 4; ++ti)
#pragma unroll
      for (int tj = 0; tj < 4; ++tj) {
        int col = j0 + wc * 64 + tj * 16 + (lane & 15);
        float bv = b2f(bias[col]);
        float wv = b2f(w3[col]);
#pragma unroll
        for (int r = 0; r < 4; ++r) {
          float v = fmaxf(acc[ti][tj][r] + bv, 0.0f);
          part[ti][r] += v * wv;
        }
      }
#pragma unroll
    for (int ti = 0; ti < 4; ++ti)
#pragma unroll
      for (int r = 0; r < 4; ++r) {
        float s = part[ti][r];
        s += __shfl_xor(s, 1);
        s += __shfl_xor(s, 2);
        s += __shfl_xor(s, 4);
        s += __shfl_xor(s, 8);
        if ((lane & 15) == 0) {
          int row = n0 + wr * 64 + ti * 16 + ((lane >> 4) << 2) + r;
          if (row < NN) unsafeAtomicAdd(&out1acc[row], s);
        }
      }
  } else {
#pragma unroll
    for (int ti = 0; ti < 4; ++ti)
#pragma unroll
      for (int tj = 0; tj < 4; ++tj) {
        int col = j0 + wc * 64 + tj * 16 + (lane & 15);
        float bv = b2f(bias[col]);
#pragma unroll
        for (int r = 0; r < 4; ++r) {
          int row = n0 + wr * 64 + ti * 16 + ((lane >> 4) << 2) + r;
          if (row < NN) {
            float v = fmaxf(acc[ti][tj][r] + bv, 0.0f);
            x2v[(size_t)row * 256 + (col - 256)] = f2b(v);
          }
        }
      }
  }
}

// ---------------------------------------------------------------------------
// R20 bilinear: OCCUPANCY experiment. All prior structures ran 7-10 waves/CU
// (acc[4][4]=64 AGPR capped residency at 2 blocks) and no pipe was saturated
// -> latency-bound. New shape: BM=64 x BN=128, 4 waves of 64x32 outputs,
// acc[4][2]=32 AGPR, NO in-loop xv capture (epilogue re-reads x2 from hot L2,
// R18-proven), LDS 25 KB, launch_bounds(256,4) -> 4-5 blocks/CU (2-2.5x TLP).
// K-loop keeps the proven R13 2-barrier form. Epilogue: cross-wave LDS reduce
// -> ONE 64-lane atomic per block (line-RMWs 8x down; WRITE 80MB anomaly).
// ---------------------------------------------------------------------------
__device__ __forceinline__ void stage64(const u16* __restrict__ src,
                                        int row0, int maxRow, int k0,
                                        u16* lds, int w, int lane) {
  int rsel = lane >> 3;
  int gch = (lane & 7) ^ rsel;
#pragma unroll
  for (int i = 0; i < 2; ++i) {
    int rb = (w * 2 + i) * 8;          // 4 waves x 2 groups x 8 rows = 64 rows
    int grow = row0 + rb + rsel;
    grow = grow > maxRow ? maxRow : grow;
    const u16* gp = src + (size_t)grow * 256 + k0 + gch * 8;
    u16* lp = lds + rb * 64;
    __builtin_amdgcn_global_load_lds(
        (const __attribute__((address_space(1))) void*)gp,
        (__attribute__((address_space(3))) void*)lp, 16, 0, 0);
  }
}

__global__ __launch_bounds__(256, 4)
void bilinear_tlp_kernel(const u16* __restrict__ x2v, const u16* __restrict__ W,
                         float* __restrict__ out2acc, int NN) {
  __shared__ u16 lA[64 * 64];     // 8 KB  (x2 tile: 64 rows x 64 k)
  __shared__ u16 lB[128 * 64];    // 16 KB (W tile: 128 rows x 64 k)
  __shared__ float sc[64 * 4];    // 1 KB  (cross-wave reduce scratch)
  int lane = threadIdx.x & 63;
  int w = threadIdx.x >> 6;       // 0..3 = column-quarter of the 128 W rows
  int n0 = blockIdx.y * 64;
  int rm0 = blockIdx.x * 128;
  int m0g = rm0 & 255;            // x2-column offset of this W block
  int region = rm0 >> 8;

  f32x4 acc[4][2];
#pragma unroll
  for (int i = 0; i < 4; ++i)
#pragma unroll
    for (int j = 0; j < 2; ++j) acc[i][j] = (f32x4){0.f, 0.f, 0.f, 0.f};

#pragma unroll
  for (int kt4 = 0; kt4 < 4; ++kt4) {
    stage64(x2v, n0, NN - 1, kt4 * 64, lA, w, lane);
    stage_async(W, 256, rm0, 16383, kt4 * 64, lB, w, lane);
    __syncthreads();
#pragma unroll
    for (int ks = 0; ks < 2; ++ks) {
      bf16x8 af[4], bfr[2];
      int g = ks * 4 + (lane >> 4);
#pragma unroll
      for (int t = 0; t < 4; ++t) {
        int rowA = t * 16 + (lane & 15);
        af[t] = *(const bf16x8*)(lA + rowA * 64 + ((g ^ (rowA & 7)) * 8));
      }
#pragma unroll
      for (int u = 0; u < 2; ++u) {
        int rowB = w * 32 + u * 16 + (lane & 15);
        bfr[u] = *(const bf16x8*)(lB + rowB * 64 + ((g ^ (rowB & 7)) * 8));
      }
#pragma unroll
      for (int t = 0; t < 4; ++t)
#pragma unroll
        for (int u = 0; u < 2; ++u)
          acc[t][u] = __builtin_amdgcn_mfma_f32_16x16x32_bf16(af[t], bfr[u],
                                                              acc[t][u], 0, 0, 0);
    }
    __syncthreads();
  }

  // epilogue: dot with x2 (re-read from L2), 16-lane shfl reduce,
  // cross-wave LDS reduce, ONE 64-lane atomic per block.
#pragma unroll
  for (int ti = 0; ti < 4; ++ti)
#pragma unroll
    for (int r = 0; r < 4; ++r) {
      int rowl = ti * 16 + ((lane >> 4) << 2) + r;
      int row = n0 + rowl;
      int rc = row < NN ? row : NN - 1;
      const u16* xr = x2v + (size_t)rc * 256 + m0g + w * 32 + (lane & 15);
      float s = acc[ti][0][r] * b2f(xr[0]) + acc[ti][1][r] * b2f(xr[16]);
      s += __shfl_xor(s, 1);
      s += __shfl_xor(s, 2);
      s += __shfl_xor(s, 4);
      s += __shfl_xor(s, 8);
      if ((lane & 15) == 0) sc[rowl * 4 + w] = s;
    }
  __syncthreads();
  int tid = threadIdx.x;
  if (tid < 64) {
    float s = sc[tid * 4] + sc[tid * 4 + 1] + sc[tid * 4 + 2] + sc[tid * 4 + 3];
    int nn = n0 + tid;
    if (nn < NN) unsafeAtomicAdd(&out2acc[(size_t)nn * 64 + region], s);
  }
}

// --------------------- edge sort (scan/place) + gather ----------------------
__global__ void scan_kernel(const int* __restrict__ count, int* __restrict__ start,
                            int* __restrict__ cursor, float* __restrict__ dinv) {
  __shared__ int wsum[16];
  __shared__ int carry_s;
  int t = threadIdx.x;          // 1024 threads = 16 waves
  int wv = t >> 6, ln = t & 63;
  if (t == 0) carry_s = 0;
  __syncthreads();
  for (int base = 0; base < N_NODES; base += 1024) {
    int i = base + t;
    int v = (i < N_NODES) ? count[i] : 0;
    int s = v;
#pragma unroll
    for (int o = 1; o < 64; o <<= 1) {
      int u = __shfl_up(s, o);
      if (ln >= o) s += u;
    }
    if (ln == 63) wsum[wv] = s;
    __syncthreads();
    if (wv == 0) {
      int x = (ln < 16) ? wsum[ln] : 0;
#pragma unroll
      for (int o = 1; o < 16; o <<= 1) {
        int u = __shfl_up(x, o);
        if (ln >= o) x += u;
      }
      if (ln < 16) wsum[ln] = x;
    }
    __syncthreads();
    int excl = s - v + (wv ? wsum[wv - 1] : 0) + carry_s;
    if (i < N_NODES) {
      start[i] = excl;
      cursor[i] = excl;
      dinv[i] = rsqrtf(1.0f + (float)v);
    }
    __syncthreads();
    if (t == 0) carry_s += wsum[15];
    __syncthreads();
  }
}

__global__ void place_kernel(const int* __restrict__ ei, int* __restrict__ cursor,
                             int* __restrict__ order) {
  int i = blockIdx.x * 256 + threadIdx.x;
  if (i >= E_EDGES) return;
  int d = ei[E_EDGES + i];
  int pos = atomicAdd(&cursor[d], 1);
  order[pos] = i;
}

__global__ void gather_kernel(const int* __restrict__ ei, const int* __restrict__ order,
                              const int* __restrict__ start, const int* __restrict__ count,
                              const float* __restrict__ dinv, const float* __restrict__ xw,
                              const u16* __restrict__ conv_b, const u16* __restrict__ x,
                              u16* __restrict__ x0) {
  int node = (blockIdx.x * blockDim.x + threadIdx.x) >> 6;
  int lane = threadIdx.x & 63;
  if (node >= N_NODES) return;
  int s0 = start[node], cnt = count[node];
  float dn = dinv[node];
  float ax = 0.f, ay = 0.f, az = 0.f, aw = 0.f;
  for (int base = 0; base < cnt; base += 64) {
    int rem = cnt - base;
    int m = rem < 64 ? rem : 64;
    int eid = (lane < m) ? order[s0 + base + lane] : 0;
    int s = (lane < m) ? ei[eid] : 0;
    float nrm = (lane < m) ? dinv[s] * dn : 0.f;
    for (int j = 0; j < m; ++j) {
      int sj = __shfl(s, j);
      float nj = __shfl(nrm, j);
      float4 v = *((const float4*)(xw + (size_t)sj * 256) + lane);
      ax += nj * v.x; ay += nj * v.y; az += nj * v.z; aw += nj * v.w;
    }
  }
  float4 sv = *((const float4*)(xw + (size_t)node * 256) + lane);
  float slw = dn * dn;
  const u16* bb = conv_b + lane * 4;
  const u16* xr = x + (size_t)node * 256 + lane * 4;
  u16 o[4];
  float vals[4] = {ax + slw * sv.x, ay + slw * sv.y, az + slw * sv.z, aw + slw * sv.w};
#pragma unroll
  for (int j = 0; j < 4; ++j) {
    float v = vals[j] + b2f(bb[j]);
    v = fmaxf(v, 0.0f) + b2f(xr[j]);
    o[j] = f2b(v);
  }
  *((ushort4*)(x0 + (size_t)node * 256) + lane) = make_ushort4(o[0], o[1], o[2], o[3]);
}

// ------------------------------- final output -------------------------------
__global__ void out_final_kernel(const float* __restrict__ out1acc,
                                 const float* __restrict__ out2acc,
                                 const u16* __restrict__ b3, const u16* __restrict__ bb,
                                 void* __restrict__ dout, const int* __restrict__ flag) {
  int idx = blockIdx.x * 256 + threadIdx.x;
  int f = *flag;
  if (idx < N_NODES) {
    float v = out1acc[idx] + b2f(b3[0]);
    if (f) ((u16*)dout)[idx] = f2b(v);
    else   ((float*)dout)[idx] = v;
  } else if (idx < N_NODES + N_NODES * 64) {
    int k = idx - N_NODES;
    float v = out2acc[k] + b2f(bb[k & 63]);
    if (f) ((u16*)dout)[idx] = f2b(v);
    else   ((float*)dout)[idx] = v;
  }
}

// ----------------------------------------------------------------------------
extern "C" void kernel_launch(void* const* d_in, const int* in_sizes, int n_in,
                              void* d_out, int out_size, void* d_ws, size_t ws_size,
                              hipStream_t stream) {
  const int* ei = (const int*)d_in[1];

  float* ws      = (float*)d_ws;
  float* xw      = ws;                          // [N,256] f32
  int*   count   = (int*)(xw + N_NODES * 256);  // [N]
  int*   start   = count + 10240;               // [N]
  int*   cursor  = start + 10240;               // [N]
  int*   order   = cursor + 10240;              // [E]
  float* dinv    = (float*)(order + E_EDGES);   // [N]
  float* out1acc = dinv + 10240;                // [N] (padded 10240)
  float* out2acc = out1acc + 10240;             // [N,64] (adjacent: one memset)
  u16* x0  = (u16*)(out2acc + N_NODES * 64);    // [N,256] bf16
  u16* x0m = x0 + N_NODES * 256;
  u16* x2v = x0m + N_NODES * 256;
  // canonical bf16 inputs — cx..cwB CONTIGUOUS (canon_all relies on this)
  u16* cx  = x2v + N_NODES * 256;
  u16* cwc = cx + CX_N;
  u16* cw1 = cwc + W_N;
  u16* cw2 = cw1 + W_N;                         // cw2, cw4 contiguous = [512,256]
  u16* cw4 = cw2 + W_N;
  u16* cwB = cw4 + W_N;
  u16* cbc = cwB + WB_N;
  u16* cb1 = cbc + 256;
  u16* cb2 = cb1 + 256;                         // cb2, cb4 contiguous = [512]
  u16* cb4 = cb2 + 256;
  u16* cw3 = cb4 + 256;
  u16* cbB = cw3 + 256;
  u16* cb3 = cbB + 64;
  int* flag = (int*)(cb3 + 16);

  hipMemsetAsync(count, 0, N_NODES * sizeof(int), stream);
  hipMemsetAsync(out1acc, 0, (10240 + (size_t)N_NODES * 64) * sizeof(float), stream);

  detect_kernel<<<1, 64, 0, stream>>>((const unsigned*)d_in[0], flag);

  canon_all_kernel<<<CANON_BIG_BLOCKS + 1 + HIST_BLOCKS, 256, 0, stream>>>(
      d_in[0], d_in[2], d_in[4], d_in[6], d_in[10], d_in[12],
      d_in[3], d_in[5], d_in[7], d_in[11], d_in[8], d_in[13], d_in[9],
      cx, cbc, cb1, cb2, cb4, cw3, cbB, cb3,
      ei, count, flag);

  scan_kernel<<<1, 1024, 0, stream>>>(count, start, cursor, dinv);
  place_kernel<<<(E_EDGES + 255) / 256, 256, 0, stream>>>(ei, cursor, order);

  gemm_kernel<false, true><<<dim3(2, 79), 256, 0, stream>>>(
      cx, cwc, nullptr, xw, nullptr, N_NODES, 256, 256);

  gather_kernel<<<(N_NODES * 64 + 255) / 256, 256, 0, stream>>>(
      ei, order, start, count, dinv, xw, cbc, cx, x0);

  gemm_kernel<true, false><<<dim3(2, 79), 256, 0, stream>>>(
      x0, cw1, cb1, nullptr, x0m, N_NODES, 256, 256);

  gemm_fused234_kernel<<<dim3(4, 79), 256, 0, stream>>>(
      x0m, cw2, cb2, cw3, out1acc, x2v, N_NODES);

  // 157 n-tiles of 64 rows (157*64 = 10048 >= 10000), 128 W-tiles
  bilinear_tlp_kernel<<<dim3(128, 157), 256, 0, stream>>>(x2v, cwB, out2acc, N_NODES);

  out_final_kernel<<<(N_NODES * 65 + 255) / 256, 256, 0, stream>>>(
      out1acc, out2acc, cb3, cbB, d_out, flag);
}